// Round 7
// baseline (514.684 us; speedup 1.0000x reference)
//
#include <hip/hip_runtime.h>

#define NN 20000
#define EE 320000
#define FIN 200
#define HH 128
#define CC 10
#define GG 100
#define BN_EPS 1e-5f

typedef __attribute__((ext_vector_type(8))) short bf16x8;
typedef __attribute__((ext_vector_type(4))) float f32x4;

__device__ __forceinline__ ushort bf16rn(float x) {
    uint u = __float_as_uint(x);
    u += 0x7FFFu + ((u >> 16) & 1u);
    return (ushort)(u >> 16);
}

// ---------------------------------------------------------------------------
// MFMA GEMM (split-bf16): Croot[M,128] = A@Wroot^T (+bias), Crel = A@Wrel^T
// A*W = Ahi*Whi + Alo*Whi + Ahi*Wlo  (lo*lo dropped, ~2^-17 rel err).
// W combined [256][Kp] row-major bf16 (rows 0-127 root, 128-255 rel).
// Block 512 thr = 8 waves, tile 32 rows. Wave w: mat = w>>2 (root/rel),
// col-slice (w&3)*32 .. +31 (2 nf), 2 mf; acc 16 VGPR/thread.
// Grid 625 x 8 waves = 5000 waves (~4.9/SIMD) to hide W-load latency.
// Fragment layouts (mfma_f32_16x16x32_bf16): lane reads 8 contiguous k
// -> direct 16B global loads, no LDS, no transpose.
// ---------------------------------------------------------------------------
template<int NSRC, bool CVT>
__global__ __launch_bounds__(512)
void gemm_mfma(const ushort* __restrict__ A0h, const ushort* __restrict__ A0l,
               const ushort* __restrict__ A1h, const ushort* __restrict__ A1l,
               const ushort* __restrict__ A2h, const ushort* __restrict__ A2l,
               const ushort* __restrict__ A3h, const ushort* __restrict__ A3l,
               int KA,                       // per-source K / A row stride
               const ushort* __restrict__ Wh, const ushort* __restrict__ Wl,
               int Kp,                       // W row stride (padded total K)
               const float* __restrict__ bias,
               float* __restrict__ Croot, float* __restrict__ Crel, int M)
{
    const int wid    = threadIdx.x >> 6;    // 0..7
    const int lane   = threadIdx.x & 63;
    const int l15    = lane & 15;
    const int koff   = (lane >> 4) * 8;
    const int m0     = blockIdx.x * 32;
    const int matsel = wid >> 2;            // 0: root, 1: rel
    const int nqb    = (wid & 3) * 32;      // col base within 128
    f32x4 acc[2][2] = {};
    int r0 = m0 + l15;      if (r0 >= M) r0 = M - 1;
    int r1 = m0 + 16 + l15; if (r1 >= M) r1 = M - 1;
    const int ksteps = (Kp + 31) / 32;

    for (int ks = 0; ks < ksteps; ++ks) {
        const int kb = ks * 32;
        bf16x8 ah[2], al[2];
        if (CVT) {
            const float* __restrict__ A = (const float*)A0h;
            #pragma unroll
            for (int mf = 0; mf < 2; ++mf) {
                const int r = mf ? r1 : r0;
                const float* __restrict__ base = &A[(size_t)r * KA];
                #pragma unroll
                for (int j = 0; j < 8; ++j) {
                    const int k = kb + koff + j;
                    const float v = (k < KA) ? base[k] : 0.f;
                    const ushort h = bf16rn(v);
                    const float hf = __uint_as_float((uint)h << 16);
                    ah[mf][j] = (short)h;
                    al[mf][j] = (short)bf16rn(v - hf);
                }
            }
        } else {
            int kl = kb;
            const ushort* __restrict__ Ah = A0h;
            const ushort* __restrict__ Al = A0l;
            if (NSRC == 4) {
                const int src = kb >> 7;
                kl = kb & 127;
                Ah = (src == 0) ? A0h : (src == 1) ? A1h : (src == 2) ? A2h : A3h;
                Al = (src == 0) ? A0l : (src == 1) ? A1l : (src == 2) ? A2l : A3l;
            }
            ah[0] = *(const bf16x8*)&Ah[(size_t)r0 * KA + kl + koff];
            al[0] = *(const bf16x8*)&Al[(size_t)r0 * KA + kl + koff];
            ah[1] = *(const bf16x8*)&Ah[(size_t)r1 * KA + kl + koff];
            al[1] = *(const bf16x8*)&Al[(size_t)r1 * KA + kl + koff];
        }
        #pragma unroll
        for (int nf = 0; nf < 2; ++nf) {
            const int wr = matsel * 128 + nqb + nf * 16 + l15;
            const bf16x8 wh = *(const bf16x8*)&Wh[(size_t)wr * Kp + kb + koff];
            const bf16x8 wl = *(const bf16x8*)&Wl[(size_t)wr * Kp + kb + koff];
            acc[0][nf] = __builtin_amdgcn_mfma_f32_16x16x32_bf16(ah[0], wh, acc[0][nf], 0, 0, 0);
            acc[0][nf] = __builtin_amdgcn_mfma_f32_16x16x32_bf16(al[0], wh, acc[0][nf], 0, 0, 0);
            acc[0][nf] = __builtin_amdgcn_mfma_f32_16x16x32_bf16(ah[0], wl, acc[0][nf], 0, 0, 0);
            acc[1][nf] = __builtin_amdgcn_mfma_f32_16x16x32_bf16(ah[1], wh, acc[1][nf], 0, 0, 0);
            acc[1][nf] = __builtin_amdgcn_mfma_f32_16x16x32_bf16(al[1], wh, acc[1][nf], 0, 0, 0);
            acc[1][nf] = __builtin_amdgcn_mfma_f32_16x16x32_bf16(ah[1], wl, acc[1][nf], 0, 0, 0);
        }
    }

    // epilogue: C/D layout col=lane&15, row=(lane>>4)*4+j
    float* __restrict__ C = matsel ? Crel : Croot;
    const int rowb = (lane >> 4) * 4;
    #pragma unroll
    for (int mf = 0; mf < 2; ++mf) {
        #pragma unroll
        for (int nf = 0; nf < 2; ++nf) {
            const int col = nqb + nf * 16 + l15;
            const float bv = (matsel == 0 && bias) ? bias[col] : 0.f;
            #pragma unroll
            for (int j = 0; j < 4; ++j) {
                const int row = m0 + mf * 16 + rowb + j;
                if (row < M) C[(size_t)row * HH + col] = acc[mf][nf][j] + bv;
            }
        }
    }
}

// ---------------------------------------------------------------------------
// weight split: Wc_hi/lo[256][Kp] bf16 from Wroot/Wrel [128][K] fp32
// ---------------------------------------------------------------------------
__global__ void split_w(const float* __restrict__ Wroot, const float* __restrict__ Wrel,
                        int K, int Kp, ushort* __restrict__ Wh, ushort* __restrict__ Wl,
                        int total)
{
    int i = blockIdx.x * blockDim.x + threadIdx.x;
    if (i >= total) return;
    const int row = i / Kp, col = i - row * Kp;
    float v = 0.f;
    if (col < K) v = (row < 128) ? Wroot[row * K + col] : Wrel[(row - 128) * K + col];
    const ushort h = bf16rn(v);
    const float hf = __uint_as_float((uint)h << 16);
    Wh[i] = h;
    Wl[i] = bf16rn(v - hf);
}

// ---------------------------------------------------------------------------
// CSR build
// ---------------------------------------------------------------------------
__global__ void hist_k(const int* __restrict__ ei, int* __restrict__ deg)
{
    int e = blockIdx.x * blockDim.x + threadIdx.x;
    if (e < EE) atomicAdd(&deg[ei[EE + e]], 1);
}

__global__ __launch_bounds__(1024)
void scan_k(const int* __restrict__ deg, int* __restrict__ row_ptr,
            int* __restrict__ pos)
{
    __shared__ int part[1024];
    const int t = threadIdx.x;
    const int chunk = (NN + 1023) / 1024;
    const int i0 = t * chunk;
    const int i1 = min(i0 + chunk, NN);
    int s = 0;
    for (int i = i0; i < i1; ++i) s += deg[i];
    part[t] = s;
    __syncthreads();
    for (int off = 1; off < 1024; off <<= 1) {
        int v = (t >= off) ? part[t - off] : 0;
        __syncthreads();
        part[t] += v;
        __syncthreads();
    }
    int run = (t == 0) ? 0 : part[t - 1];
    for (int i = i0; i < i1; ++i) {
        const int d = deg[i];
        row_ptr[i] = run;
        pos[i] = run;
        run += d;
    }
    if (t == 0) row_ptr[NN] = part[1023];
}

__global__ void fill_k(const int* __restrict__ ei, int* __restrict__ pos,
                       int* __restrict__ eidx)
{
    int e = blockIdx.x * blockDim.x + threadIdx.x;
    if (e < EE) {
        const int slot = atomicAdd(&pos[ei[EE + e]], 1);
        eidx[slot] = ei[e];
    }
}

// ---------------------------------------------------------------------------
// gather + ReLU + hi/lo bf16 split (output feeds next MFMA GEMM)
// ---------------------------------------------------------------------------
__global__ __launch_bounds__(256)
void gather_hilo(const float* __restrict__ base, const float* __restrict__ T1,
                 const int* __restrict__ row_ptr, const int* __restrict__ eidx,
                 ushort* __restrict__ Xh, ushort* __restrict__ Xl)
{
    const int n  = blockIdx.x * 8 + (threadIdx.x >> 5);
    const int f4 = threadIdx.x & 31;
    if (n >= NN) return;
    const int e0 = row_ptr[n], e1 = row_ptr[n + 1];
    float4 a0 = *(const float4*)&base[(size_t)n * HH + f4 * 4];
    float4 a1 = {0,0,0,0}, a2 = {0,0,0,0}, a3 = {0,0,0,0};
    int e = e0;
    for (; e + 4 <= e1; e += 4) {
        const int s0 = eidx[e], s1 = eidx[e+1], s2 = eidx[e+2], s3 = eidx[e+3];
        const float4 v0 = *(const float4*)&T1[(size_t)s0 * HH + f4 * 4];
        const float4 v1 = *(const float4*)&T1[(size_t)s1 * HH + f4 * 4];
        const float4 v2 = *(const float4*)&T1[(size_t)s2 * HH + f4 * 4];
        const float4 v3 = *(const float4*)&T1[(size_t)s3 * HH + f4 * 4];
        a0.x += v0.x; a0.y += v0.y; a0.z += v0.z; a0.w += v0.w;
        a1.x += v1.x; a1.y += v1.y; a1.z += v1.z; a1.w += v1.w;
        a2.x += v2.x; a2.y += v2.y; a2.z += v2.z; a2.w += v2.w;
        a3.x += v3.x; a3.y += v3.y; a3.z += v3.z; a3.w += v3.w;
    }
    for (; e < e1; ++e) {
        const int s = eidx[e];
        const float4 v = *(const float4*)&T1[(size_t)s * HH + f4 * 4];
        a0.x += v.x; a0.y += v.y; a0.z += v.z; a0.w += v.w;
    }
    float v[4];
    v[0] = fmaxf((a0.x + a1.x) + (a2.x + a3.x), 0.f);
    v[1] = fmaxf((a0.y + a1.y) + (a2.y + a3.y), 0.f);
    v[2] = fmaxf((a0.z + a1.z) + (a2.z + a3.z), 0.f);
    v[3] = fmaxf((a0.w + a1.w) + (a2.w + a3.w), 0.f);
    ushort4 h, l;
    {
        ushort hh; float hf;
        hh = bf16rn(v[0]); hf = __uint_as_float((uint)hh << 16); h.x = hh; l.x = bf16rn(v[0] - hf);
        hh = bf16rn(v[1]); hf = __uint_as_float((uint)hh << 16); h.y = hh; l.y = bf16rn(v[1] - hf);
        hh = bf16rn(v[2]); hf = __uint_as_float((uint)hh << 16); h.z = hh; l.z = bf16rn(v[2] - hf);
        hh = bf16rn(v[3]); hf = __uint_as_float((uint)hh << 16); h.w = hh; l.w = bf16rn(v[3] - hf);
    }
    *(ushort4*)&Xh[(size_t)n * HH + f4 * 4] = h;
    *(ushort4*)&Xl[(size_t)n * HH + f4 * 4] = l;
}

// gather for layer 5: fp32, in-place on base, no relu
__global__ __launch_bounds__(256)
void gather_f32(const float* __restrict__ T1, const int* __restrict__ row_ptr,
                const int* __restrict__ eidx, float* __restrict__ X)
{
    const int n  = blockIdx.x * 8 + (threadIdx.x >> 5);
    const int f4 = threadIdx.x & 31;
    if (n >= NN) return;
    const int e0 = row_ptr[n], e1 = row_ptr[n + 1];
    float4 a0 = *(const float4*)&X[(size_t)n * HH + f4 * 4];
    float4 a1 = {0,0,0,0}, a2 = {0,0,0,0}, a3 = {0,0,0,0};
    int e = e0;
    for (; e + 4 <= e1; e += 4) {
        const int s0 = eidx[e], s1 = eidx[e+1], s2 = eidx[e+2], s3 = eidx[e+3];
        const float4 v0 = *(const float4*)&T1[(size_t)s0 * HH + f4 * 4];
        const float4 v1 = *(const float4*)&T1[(size_t)s1 * HH + f4 * 4];
        const float4 v2 = *(const float4*)&T1[(size_t)s2 * HH + f4 * 4];
        const float4 v3 = *(const float4*)&T1[(size_t)s3 * HH + f4 * 4];
        a0.x += v0.x; a0.y += v0.y; a0.z += v0.z; a0.w += v0.w;
        a1.x += v1.x; a1.y += v1.y; a1.z += v1.z; a1.w += v1.w;
        a2.x += v2.x; a2.y += v2.y; a2.z += v2.z; a2.w += v2.w;
        a3.x += v3.x; a3.y += v3.y; a3.z += v3.z; a3.w += v3.w;
    }
    for (; e < e1; ++e) {
        const int s = eidx[e];
        const float4 v = *(const float4*)&T1[(size_t)s * HH + f4 * 4];
        a0.x += v.x; a0.y += v.y; a0.z += v.z; a0.w += v.w;
    }
    float4 acc;
    acc.x = (a0.x + a1.x) + (a2.x + a3.x);
    acc.y = (a0.y + a1.y) + (a2.y + a3.y);
    acc.z = (a0.z + a1.z) + (a2.z + a3.z);
    acc.w = (a0.w + a1.w) + (a2.w + a3.w);
    *(float4*)&X[(size_t)n * HH + f4 * 4] = acc;
}

__global__ void zero_k(float* __restrict__ p, int n)
{
    int i = blockIdx.x * blockDim.x + threadIdx.x;
    if (i < n) p[i] = 0.f;
}

__global__ __launch_bounds__(256)
void bn_stats(const float* __restrict__ x5, float* __restrict__ stats)
{
    __shared__ float sh_s[256], sh_q[256];
    const int f    = threadIdx.x & 127;
    const int half = threadIdx.x >> 7;
    const int rpb  = (NN + gridDim.x - 1) / gridDim.x;
    const int r0   = blockIdx.x * rpb;
    const int r1   = min(r0 + rpb, NN);
    float s = 0.f, q = 0.f;
    for (int r = r0 + half; r < r1; r += 2) {
        const float v = x5[(size_t)r * HH + f];
        s += v; q += v * v;
    }
    sh_s[threadIdx.x] = s; sh_q[threadIdx.x] = q;
    __syncthreads();
    if (half == 0) {
        s += sh_s[128 + f]; q += sh_q[128 + f];
        atomicAdd(&stats[f], s);
        atomicAdd(&stats[128 + f], q);
    }
}

__global__ __launch_bounds__(128)
void pool_sum(const float* __restrict__ x5, const int* __restrict__ batch,
              float* __restrict__ pool)
{
    const int f  = threadIdx.x;
    const int n0 = blockIdx.x * 64;
    const int n1 = min(n0 + 64, NN);
    float acc = 0.f;
    int curg = batch[n0];
    for (int n = n0; n < n1; ++n) {
        const int g = batch[n];
        if (g != curg) {
            atomicAdd(&pool[(size_t)curg * HH + f], acc);
            acc = 0.f; curg = g;
        }
        acc += x5[(size_t)n * HH + f];
    }
    atomicAdd(&pool[(size_t)curg * HH + f], acc);
}

__global__ __launch_bounds__(128)
void finalize(const float* __restrict__ stats, const float* __restrict__ pool,
              const int* __restrict__ batch,
              const float* __restrict__ gamma, const float* __restrict__ beta,
              const float* __restrict__ lin_w, const float* __restrict__ lin_b,
              float* __restrict__ out)
{
    const int g = blockIdx.x, f = threadIdx.x;
    __shared__ int seg[2];
    if (f < 2) {
        const int target = g + f;
        int lo = 0, hi = NN;
        while (lo < hi) {
            const int mid = (lo + hi) >> 1;
            if (batch[mid] < target) lo = mid + 1; else hi = mid;
        }
        seg[f] = lo;
    }
    __syncthreads();
    const float c   = (float)(seg[1] - seg[0]);
    const float mu  = stats[f] * (1.0f / NN);
    const float var = stats[128 + f] * (1.0f / NN) - mu * mu;
    const float scale = gamma[f] * rsqrtf(var + BN_EPS);
    const float pm = pool[(size_t)g * HH + f] / fmaxf(c, 1.0f);
    __shared__ float sh[128];
    sh[f] = (pm - mu) * scale + beta[f];
    __syncthreads();
    if (f < CC) {
        float s = lin_b[f];
        #pragma unroll 8
        for (int k = 0; k < HH; ++k) s += sh[k] * lin_w[f * HH + k];
        out[(size_t)g * CC + f] = s;
    }
}

extern "C" void kernel_launch(void* const* d_in, const int* in_sizes, int n_in,
                              void* d_out, int out_size, void* d_ws, size_t ws_size,
                              hipStream_t stream)
{
    const float* x       = (const float*)d_in[0];
    const int*   ei      = (const int*)d_in[1];
    const int*   batch   = (const int*)d_in[2];
    const float* w1_rel  = (const float*)d_in[3];
    const float* w1_root = (const float*)d_in[4];
    const float* b1      = (const float*)d_in[5];
    const float* w2_rel  = (const float*)d_in[6];
    const float* w2_root = (const float*)d_in[7];
    const float* b2      = (const float*)d_in[8];
    const float* w3_rel  = (const float*)d_in[9];
    const float* w3_root = (const float*)d_in[10];
    const float* b3      = (const float*)d_in[11];
    const float* w4_rel  = (const float*)d_in[12];
    const float* w4_root = (const float*)d_in[13];
    const float* b4      = (const float*)d_in[14];
    const float* w5_rel  = (const float*)d_in[15];   // [128, 512]
    const float* w5_root = (const float*)d_in[16];   // [128, 512]
    const float* b5      = (const float*)d_in[17];
    const float* gamma   = (const float*)d_in[18];
    const float* beta    = (const float*)d_in[19];
    const float* lin_w   = (const float*)d_in[20];
    const float* lin_b   = (const float*)d_in[21];
    float* out = (float*)d_out;

    const size_t NH = (size_t)NN * HH;   // 2,560,000
    float*  XR  = (float*)d_ws;          // root GEMM out; becomes X5 in-place
    float*  T1  = XR + NH;               // rel GEMM out
    ushort* X1h = (ushort*)(T1 + NH);
    ushort* X1l = X1h + NH;
    ushort* X2h = X1l + NH;
    ushort* X2l = X2h + NH;
    ushort* X3h = X2l + NH;
    ushort* X3l = X3h + NH;
    ushort* X4h = X3l + NH;
    ushort* X4l = X4h + NH;
    const int K1P = 224;                 // 200 padded to 7*32
    ushort* W1h = X4l + NH;              // [256][224]
    ushort* W1l = W1h + 256 * K1P;
    ushort* W2h = W1l + 256 * K1P;       // [256][128] x3 layers
    ushort* W2l = W2h + 256 * 128;
    ushort* W3h = W2l + 256 * 128;
    ushort* W3l = W3h + 256 * 128;
    ushort* W4h = W3l + 256 * 128;
    ushort* W4l = W4h + 256 * 128;
    ushort* W5h = W4l + 256 * 128;       // [256][512]
    ushort* W5l = W5h + 256 * 512;
    float*  STATS = (float*)(W5l + 256 * 512);   // 256
    float*  POOL  = STATS + 256;                 // GG*HH
    int* row_ptr = (int*)(POOL + (size_t)GG * HH);  // NN+1
    int* pos     = row_ptr + (NN + 1);
    int* deg     = pos + NN;
    int* eidx    = deg + NN;
    const size_t need = (size_t)(eidx + EE) - (size_t)d_ws;
    if (ws_size < need) return;

    const dim3 blk(256);
    const int ggemm = (NN + 31) / 32;       // 625 blocks x 512 thr
    const int gedge = (EE + 255) / 256;
    const int ggath = (NN + 7) / 8;

    zero_k<<<(256 + GG * HH + 255) / 256, blk, 0, stream>>>(STATS, 256 + GG * HH);
    zero_k<<<(NN + 255) / 256, blk, 0, stream>>>((float*)deg, NN);

    // CSR build
    hist_k<<<gedge, blk, 0, stream>>>(ei, deg);
    scan_k<<<1, dim3(1024), 0, stream>>>(deg, row_ptr, pos);
    fill_k<<<gedge, blk, 0, stream>>>(ei, pos, eidx);

    // weight hi/lo splits
    split_w<<<(256 * K1P + 255) / 256, blk, 0, stream>>>(w1_root, w1_rel, FIN, K1P, W1h, W1l, 256 * K1P);
    split_w<<<(256 * 128 + 255) / 256, blk, 0, stream>>>(w2_root, w2_rel, HH, 128, W2h, W2l, 256 * 128);
    split_w<<<(256 * 128 + 255) / 256, blk, 0, stream>>>(w3_root, w3_rel, HH, 128, W3h, W3l, 256 * 128);
    split_w<<<(256 * 128 + 255) / 256, blk, 0, stream>>>(w4_root, w4_rel, HH, 128, W4h, W4l, 256 * 128);
    split_w<<<(256 * 512 + 255) / 256, blk, 0, stream>>>(w5_root, w5_rel, 512, 512, W5h, W5l, 256 * 512);

    const ushort* xu = (const ushort*)x;    // CVT path casts back to float*
    // layer 1 (A = fp32 x, K=200, converted in-register; W padded to 224)
    gemm_mfma<1, true ><<<ggemm, dim3(512), 0, stream>>>(xu, xu, xu, xu, xu, xu, xu, xu,
                                                         FIN, W1h, W1l, K1P, b1, XR, T1, NN);
    gather_hilo<<<ggath, blk, 0, stream>>>(XR, T1, row_ptr, eidx, X1h, X1l);
    // layer 2
    gemm_mfma<1, false><<<ggemm, dim3(512), 0, stream>>>(X1h, X1l, X1h, X1l, X1h, X1l, X1h, X1l,
                                                         HH, W2h, W2l, 128, b2, XR, T1, NN);
    gather_hilo<<<ggath, blk, 0, stream>>>(XR, T1, row_ptr, eidx, X2h, X2l);
    // layer 3
    gemm_mfma<1, false><<<ggemm, dim3(512), 0, stream>>>(X2h, X2l, X2h, X2l, X2h, X2l, X2h, X2l,
                                                         HH, W3h, W3l, 128, b3, XR, T1, NN);
    gather_hilo<<<ggath, blk, 0, stream>>>(XR, T1, row_ptr, eidx, X3h, X3l);
    // layer 4
    gemm_mfma<1, false><<<ggemm, dim3(512), 0, stream>>>(X3h, X3l, X3h, X3l, X3h, X3l, X3h, X3l,
                                                         HH, W4h, W4l, 128, b4, XR, T1, NN);
    gather_hilo<<<ggath, blk, 0, stream>>>(XR, T1, row_ptr, eidx, X4h, X4l);
    // layer 5: concat(x1..x4) @ W5, K=512 over 4 hi/lo sources
    gemm_mfma<4, false><<<ggemm, dim3(512), 0, stream>>>(X1h, X1l, X2h, X2l, X3h, X3l, X4h, X4l,
                                                         HH, W5h, W5l, 512, b5, XR, T1, NN);
    gather_f32<<<ggath, blk, 0, stream>>>(T1, row_ptr, eidx, XR);   // X5 := XR in-place

    // BN stats, pooling, epilogue
    bn_stats<<<80, blk, 0, stream>>>(XR, STATS);
    pool_sum<<<(NN + 63) / 64, dim3(128), 0, stream>>>(XR, batch, POOL);
    finalize<<<GG, dim3(128), 0, stream>>>(STATS, POOL, batch, gamma, beta, lin_w, lin_b, out);
}

// Round 10
// 422.324 us; speedup vs baseline: 1.2187x; 1.2187x over previous
//
#include <hip/hip_runtime.h>

#define NN 20000
#define EE 320000
#define FIN 200
#define HH 128
#define CC 10
#define GG 100
#define BN_EPS 1e-5f
#define RPB 80          // rows per gemm_wreg block; 250 blocks x 80 = 20000

typedef __attribute__((ext_vector_type(8))) short bf16x8;
typedef __attribute__((ext_vector_type(4))) float f32x4;

__device__ __forceinline__ ushort bf16rn(float x) {
    uint u = __float_as_uint(x);
    u += 0x7FFFu + ((u >> 16) & 1u);
    return (ushort)(u >> 16);
}

// ---------------------------------------------------------------------------
// R6-proven MFMA GEMM (split-bf16), 128 thr = 2 waves, tile 32 rows.
// Used for layer 1 (CVT fp32->hi/lo in-register) and layer 5 (NSRC=4 concat).
// ---------------------------------------------------------------------------
template<int NSRC, bool CVT>
__global__ __launch_bounds__(128)
void gemm_mfma(const ushort* __restrict__ A0h, const ushort* __restrict__ A0l,
               const ushort* __restrict__ A1h, const ushort* __restrict__ A1l,
               const ushort* __restrict__ A2h, const ushort* __restrict__ A2l,
               const ushort* __restrict__ A3h, const ushort* __restrict__ A3l,
               int KA,
               const ushort* __restrict__ Wh, const ushort* __restrict__ Wl,
               int Kp,
               const float* __restrict__ bias,
               float* __restrict__ Croot, float* __restrict__ Crel, int M)
{
    const int wid  = threadIdx.x >> 6;      // 0: root cols, 1: rel cols
    const int lane = threadIdx.x & 63;
    const int l15  = lane & 15;
    const int koff = (lane >> 4) * 8;
    const int m0   = blockIdx.x * 32;
    const int nbase = wid * 128;
    f32x4 acc[2][8] = {};
    int r0 = m0 + l15;      if (r0 >= M) r0 = M - 1;
    int r1 = m0 + 16 + l15; if (r1 >= M) r1 = M - 1;
    const int ksteps = (Kp + 31) / 32;

    for (int ks = 0; ks < ksteps; ++ks) {
        const int kb = ks * 32;
        bf16x8 ah[2], al[2];
        if (CVT) {
            const float* __restrict__ A = (const float*)A0h;
            #pragma unroll
            for (int mf = 0; mf < 2; ++mf) {
                const int r = mf ? r1 : r0;
                const float* __restrict__ base = &A[(size_t)r * KA];
                #pragma unroll
                for (int j = 0; j < 8; ++j) {
                    const int k = kb + koff + j;
                    const float v = (k < KA) ? base[k] : 0.f;
                    const ushort h = bf16rn(v);
                    const float hf = __uint_as_float((uint)h << 16);
                    ah[mf][j] = (short)h;
                    al[mf][j] = (short)bf16rn(v - hf);
                }
            }
        } else {
            int kl = kb;
            const ushort* __restrict__ Ah = A0h;
            const ushort* __restrict__ Al = A0l;
            if (NSRC == 4) {
                const int src = kb >> 7;
                kl = kb & 127;
                Ah = (src == 0) ? A0h : (src == 1) ? A1h : (src == 2) ? A2h : A3h;
                Al = (src == 0) ? A0l : (src == 1) ? A1l : (src == 2) ? A2l : A3l;
            }
            ah[0] = *(const bf16x8*)&Ah[(size_t)r0 * KA + kl + koff];
            al[0] = *(const bf16x8*)&Al[(size_t)r0 * KA + kl + koff];
            ah[1] = *(const bf16x8*)&Ah[(size_t)r1 * KA + kl + koff];
            al[1] = *(const bf16x8*)&Al[(size_t)r1 * KA + kl + koff];
        }
        #pragma unroll
        for (int nf = 0; nf < 8; ++nf) {
            const int wr = nbase + nf * 16 + l15;
            const bf16x8 wh = *(const bf16x8*)&Wh[(size_t)wr * Kp + kb + koff];
            const bf16x8 wl = *(const bf16x8*)&Wl[(size_t)wr * Kp + kb + koff];
            acc[0][nf] = __builtin_amdgcn_mfma_f32_16x16x32_bf16(ah[0], wh, acc[0][nf], 0, 0, 0);
            acc[0][nf] = __builtin_amdgcn_mfma_f32_16x16x32_bf16(al[0], wh, acc[0][nf], 0, 0, 0);
            acc[0][nf] = __builtin_amdgcn_mfma_f32_16x16x32_bf16(ah[0], wl, acc[0][nf], 0, 0, 0);
            acc[1][nf] = __builtin_amdgcn_mfma_f32_16x16x32_bf16(ah[1], wh, acc[1][nf], 0, 0, 0);
            acc[1][nf] = __builtin_amdgcn_mfma_f32_16x16x32_bf16(al[1], wh, acc[1][nf], 0, 0, 0);
            acc[1][nf] = __builtin_amdgcn_mfma_f32_16x16x32_bf16(ah[1], wl, acc[1][nf], 0, 0, 0);
        }
    }

    float* __restrict__ C = wid ? Crel : Croot;
    const int rowb = (lane >> 4) * 4;
    #pragma unroll
    for (int mf = 0; mf < 2; ++mf) {
        #pragma unroll
        for (int nf = 0; nf < 8; ++nf) {
            const int col = nf * 16 + l15;
            const float bv = (wid == 0 && bias) ? bias[col] : 0.f;
            #pragma unroll
            for (int j = 0; j < 4; ++j) {
                const int row = m0 + mf * 16 + rowb + j;
                if (row < M) C[(size_t)row * HH + col] = acc[mf][nf][j] + bv;
            }
        }
    }
}

// ---------------------------------------------------------------------------
// W-in-registers GEMM for K=128 layers (2-4). Block 512 thr = 8 waves;
// wave w: mat = w>>2, local cols ncol=(w&3)*32 (2 nf). W slice (64 VGPR)
// loaded once; streams RPB rows in 16-row chunks.
// FIX vs R8/R9: C column uses LOCAL ncol only; matsel*128 belongs solely
// to the combined-W row index (R8/R9 added it to the store column, writing
// rel output one row down - the correctness failure).
// ---------------------------------------------------------------------------
__global__ __launch_bounds__(512)
void gemm_wreg(const ushort* __restrict__ Ah_, const ushort* __restrict__ Al_,
               const ushort* __restrict__ Wh, const ushort* __restrict__ Wl,
               const float* __restrict__ bias,
               float* __restrict__ Croot, float* __restrict__ Crel)
{
    const int wid  = threadIdx.x >> 6;
    const int lane = threadIdx.x & 63;
    const int l15  = lane & 15;
    const int koff = (lane >> 4) * 8;
    const int matsel = wid >> 2;
    const int ncol = (wid & 3) * 32;        // local col base within 128
    const int wbase = matsel * 128 + ncol;  // row base in combined W [256][128]
    const int rowb = (lane >> 4) * 4;
    const int rbase0 = blockIdx.x * RPB;

    bf16x8 wh[2][4], wl[2][4];
    #pragma unroll
    for (int nf = 0; nf < 2; ++nf) {
        const size_t wrow = (size_t)(wbase + nf * 16 + l15) * HH;
        #pragma unroll
        for (int ks = 0; ks < 4; ++ks) {
            wh[nf][ks] = *(const bf16x8*)&Wh[wrow + ks * 32 + koff];
            wl[nf][ks] = *(const bf16x8*)&Wl[wrow + ks * 32 + koff];
        }
    }
    float bv[2] = {0.f, 0.f};
    if (matsel == 0 && bias) { bv[0] = bias[ncol + l15]; bv[1] = bias[ncol + 16 + l15]; }
    float* __restrict__ C = matsel ? Crel : Croot;

    for (int ch = 0; ch < RPB; ch += 16) {
        const int r = rbase0 + ch + l15;
        f32x4 acc[2] = {};
        #pragma unroll
        for (int ks = 0; ks < 4; ++ks) {
            const bf16x8 ah = *(const bf16x8*)&Ah_[(size_t)r * HH + ks * 32 + koff];
            const bf16x8 al = *(const bf16x8*)&Al_[(size_t)r * HH + ks * 32 + koff];
            #pragma unroll
            for (int nf = 0; nf < 2; ++nf) {
                acc[nf] = __builtin_amdgcn_mfma_f32_16x16x32_bf16(ah, wh[nf][ks], acc[nf], 0, 0, 0);
                acc[nf] = __builtin_amdgcn_mfma_f32_16x16x32_bf16(al, wh[nf][ks], acc[nf], 0, 0, 0);
                acc[nf] = __builtin_amdgcn_mfma_f32_16x16x32_bf16(ah, wl[nf][ks], acc[nf], 0, 0, 0);
            }
        }
        #pragma unroll
        for (int nf = 0; nf < 2; ++nf) {
            const int col = ncol + nf * 16 + l15;   // local column (0..127)
            #pragma unroll
            for (int j = 0; j < 4; ++j) {
                const int row = rbase0 + ch + rowb + j;
                C[(size_t)row * HH + col] = acc[nf][j] + bv[nf];
            }
        }
    }
}

// ---------------------------------------------------------------------------
// weight split: Wc_hi/lo[256][Kp] bf16 from Wroot/Wrel [128][K] fp32
// ---------------------------------------------------------------------------
__global__ void split_w(const float* __restrict__ Wroot, const float* __restrict__ Wrel,
                        int K, int Kp, ushort* __restrict__ Wh, ushort* __restrict__ Wl,
                        int total)
{
    int i = blockIdx.x * blockDim.x + threadIdx.x;
    if (i >= total) return;
    const int row = i / Kp, col = i - row * Kp;
    float v = 0.f;
    if (col < K) v = (row < 128) ? Wroot[row * K + col] : Wrel[(row - 128) * K + col];
    const ushort h = bf16rn(v);
    const float hf = __uint_as_float((uint)h << 16);
    Wh[i] = h;
    Wl[i] = bf16rn(v - hf);
}

// ---------------------------------------------------------------------------
// CSR build
// ---------------------------------------------------------------------------
__global__ void hist_k(const int* __restrict__ ei, int* __restrict__ deg)
{
    int e = blockIdx.x * blockDim.x + threadIdx.x;
    if (e < EE) atomicAdd(&deg[ei[EE + e]], 1);
}

__global__ __launch_bounds__(1024)
void scan_k(const int* __restrict__ deg, int* __restrict__ row_ptr,
            int* __restrict__ pos)
{
    __shared__ int part[1024];
    const int t = threadIdx.x;
    const int chunk = (NN + 1023) / 1024;
    const int i0 = t * chunk;
    const int i1 = min(i0 + chunk, NN);
    int s = 0;
    for (int i = i0; i < i1; ++i) s += deg[i];
    part[t] = s;
    __syncthreads();
    for (int off = 1; off < 1024; off <<= 1) {
        int v = (t >= off) ? part[t - off] : 0;
        __syncthreads();
        part[t] += v;
        __syncthreads();
    }
    int run = (t == 0) ? 0 : part[t - 1];
    for (int i = i0; i < i1; ++i) {
        const int d = deg[i];
        row_ptr[i] = run;
        pos[i] = run;
        run += d;
    }
    if (t == 0) row_ptr[NN] = part[1023];
}

__global__ void fill_k(const int* __restrict__ ei, int* __restrict__ pos,
                       int* __restrict__ eidx)
{
    int e = blockIdx.x * blockDim.x + threadIdx.x;
    if (e < EE) {
        const int slot = atomicAdd(&pos[ei[EE + e]], 1);
        eidx[slot] = ei[e];
    }
}

// ---------------------------------------------------------------------------
// gather + ReLU + hi/lo bf16 split
// ---------------------------------------------------------------------------
__global__ __launch_bounds__(256)
void gather_hilo(const float* __restrict__ base, const float* __restrict__ T1,
                 const int* __restrict__ row_ptr, const int* __restrict__ eidx,
                 ushort* __restrict__ Xh, ushort* __restrict__ Xl)
{
    const int n  = blockIdx.x * 8 + (threadIdx.x >> 5);
    const int f4 = threadIdx.x & 31;
    if (n >= NN) return;
    const int e0 = row_ptr[n], e1 = row_ptr[n + 1];
    float4 a0 = *(const float4*)&base[(size_t)n * HH + f4 * 4];
    float4 a1 = {0,0,0,0}, a2 = {0,0,0,0}, a3 = {0,0,0,0};
    int e = e0;
    for (; e + 4 <= e1; e += 4) {
        const int s0 = eidx[e], s1 = eidx[e+1], s2 = eidx[e+2], s3 = eidx[e+3];
        const float4 v0 = *(const float4*)&T1[(size_t)s0 * HH + f4 * 4];
        const float4 v1 = *(const float4*)&T1[(size_t)s1 * HH + f4 * 4];
        const float4 v2 = *(const float4*)&T1[(size_t)s2 * HH + f4 * 4];
        const float4 v3 = *(const float4*)&T1[(size_t)s3 * HH + f4 * 4];
        a0.x += v0.x; a0.y += v0.y; a0.z += v0.z; a0.w += v0.w;
        a1.x += v1.x; a1.y += v1.y; a1.z += v1.z; a1.w += v1.w;
        a2.x += v2.x; a2.y += v2.y; a2.z += v2.z; a2.w += v2.w;
        a3.x += v3.x; a3.y += v3.y; a3.z += v3.z; a3.w += v3.w;
    }
    for (; e < e1; ++e) {
        const int s = eidx[e];
        const float4 v = *(const float4*)&T1[(size_t)s * HH + f4 * 4];
        a0.x += v.x; a0.y += v.y; a0.z += v.z; a0.w += v.w;
    }
    float v[4];
    v[0] = fmaxf((a0.x + a1.x) + (a2.x + a3.x), 0.f);
    v[1] = fmaxf((a0.y + a1.y) + (a2.y + a3.y), 0.f);
    v[2] = fmaxf((a0.z + a1.z) + (a2.z + a3.z), 0.f);
    v[3] = fmaxf((a0.w + a1.w) + (a2.w + a3.w), 0.f);
    ushort4 h, l;
    {
        ushort hh; float hf;
        hh = bf16rn(v[0]); hf = __uint_as_float((uint)hh << 16); h.x = hh; l.x = bf16rn(v[0] - hf);
        hh = bf16rn(v[1]); hf = __uint_as_float((uint)hh << 16); h.y = hh; l.y = bf16rn(v[1] - hf);
        hh = bf16rn(v[2]); hf = __uint_as_float((uint)hh << 16); h.z = hh; l.z = bf16rn(v[2] - hf);
        hh = bf16rn(v[3]); hf = __uint_as_float((uint)hh << 16); h.w = hh; l.w = bf16rn(v[3] - hf);
    }
    *(ushort4*)&Xh[(size_t)n * HH + f4 * 4] = h;
    *(ushort4*)&Xl[(size_t)n * HH + f4 * 4] = l;
}

// gather for layer 5: fp32, in-place on base, no relu
__global__ __launch_bounds__(256)
void gather_f32(const float* __restrict__ T1, const int* __restrict__ row_ptr,
                const int* __restrict__ eidx, float* __restrict__ X)
{
    const int n  = blockIdx.x * 8 + (threadIdx.x >> 5);
    const int f4 = threadIdx.x & 31;
    if (n >= NN) return;
    const int e0 = row_ptr[n], e1 = row_ptr[n + 1];
    float4 a0 = *(const float4*)&X[(size_t)n * HH + f4 * 4];
    float4 a1 = {0,0,0,0}, a2 = {0,0,0,0}, a3 = {0,0,0,0};
    int e = e0;
    for (; e + 4 <= e1; e += 4) {
        const int s0 = eidx[e], s1 = eidx[e+1], s2 = eidx[e+2], s3 = eidx[e+3];
        const float4 v0 = *(const float4*)&T1[(size_t)s0 * HH + f4 * 4];
        const float4 v1 = *(const float4*)&T1[(size_t)s1 * HH + f4 * 4];
        const float4 v2 = *(const float4*)&T1[(size_t)s2 * HH + f4 * 4];
        const float4 v3 = *(const float4*)&T1[(size_t)s3 * HH + f4 * 4];
        a0.x += v0.x; a0.y += v0.y; a0.z += v0.z; a0.w += v0.w;
        a1.x += v1.x; a1.y += v1.y; a1.z += v1.z; a1.w += v1.w;
        a2.x += v2.x; a2.y += v2.y; a2.z += v2.z; a2.w += v2.w;
        a3.x += v3.x; a3.y += v3.y; a3.z += v3.z; a3.w += v3.w;
    }
    for (; e < e1; ++e) {
        const int s = eidx[e];
        const float4 v = *(const float4*)&T1[(size_t)s * HH + f4 * 4];
        a0.x += v.x; a0.y += v.y; a0.z += v.z; a0.w += v.w;
    }
    float4 acc;
    acc.x = (a0.x + a1.x) + (a2.x + a3.x);
    acc.y = (a0.y + a1.y) + (a2.y + a3.y);
    acc.z = (a0.z + a1.z) + (a2.z + a3.z);
    acc.w = (a0.w + a1.w) + (a2.w + a3.w);
    *(float4*)&X[(size_t)n * HH + f4 * 4] = acc;
}

__global__ void zero_k(float* __restrict__ p, int n)
{
    int i = blockIdx.x * blockDim.x + threadIdx.x;
    if (i < n) p[i] = 0.f;
}

__global__ __launch_bounds__(256)
void bn_stats(const float* __restrict__ x5, float* __restrict__ stats)
{
    __shared__ float sh_s[256], sh_q[256];
    const int f    = threadIdx.x & 127;
    const int half = threadIdx.x >> 7;
    const int rpb  = (NN + gridDim.x - 1) / gridDim.x;
    const int r0   = blockIdx.x * rpb;
    const int r1   = min(r0 + rpb, NN);
    float s = 0.f, q = 0.f;
    for (int r = r0 + half; r < r1; r += 2) {
        const float v = x5[(size_t)r * HH + f];
        s += v; q += v * v;
    }
    sh_s[threadIdx.x] = s; sh_q[threadIdx.x] = q;
    __syncthreads();
    if (half == 0) {
        s += sh_s[128 + f]; q += sh_q[128 + f];
        atomicAdd(&stats[f], s);
        atomicAdd(&stats[128 + f], q);
    }
}

__global__ __launch_bounds__(128)
void pool_sum(const float* __restrict__ x5, const int* __restrict__ batch,
              float* __restrict__ pool)
{
    const int f  = threadIdx.x;
    const int n0 = blockIdx.x * 64;
    const int n1 = min(n0 + 64, NN);
    float acc = 0.f;
    int curg = batch[n0];
    for (int n = n0; n < n1; ++n) {
        const int g = batch[n];
        if (g != curg) {
            atomicAdd(&pool[(size_t)curg * HH + f], acc);
            acc = 0.f; curg = g;
        }
        acc += x5[(size_t)n * HH + f];
    }
    atomicAdd(&pool[(size_t)curg * HH + f], acc);
}

__global__ __launch_bounds__(128)
void finalize(const float* __restrict__ stats, const float* __restrict__ pool,
              const int* __restrict__ batch,
              const float* __restrict__ gamma, const float* __restrict__ beta,
              const float* __restrict__ lin_w, const float* __restrict__ lin_b,
              float* __restrict__ out)
{
    const int g = blockIdx.x, f = threadIdx.x;
    __shared__ int seg[2];
    if (f < 2) {
        const int target = g + f;
        int lo = 0, hi = NN;
        while (lo < hi) {
            const int mid = (lo + hi) >> 1;
            if (batch[mid] < target) lo = mid + 1; else hi = mid;
        }
        seg[f] = lo;
    }
    __syncthreads();
    const float c   = (float)(seg[1] - seg[0]);
    const float mu  = stats[f] * (1.0f / NN);
    const float var = stats[128 + f] * (1.0f / NN) - mu * mu;
    const float scale = gamma[f] * rsqrtf(var + BN_EPS);
    const float pm = pool[(size_t)g * HH + f] / fmaxf(c, 1.0f);
    __shared__ float sh[128];
    sh[f] = (pm - mu) * scale + beta[f];
    __syncthreads();
    if (f < CC) {
        float s = lin_b[f];
        #pragma unroll 8
        for (int k = 0; k < HH; ++k) s += sh[k] * lin_w[f * HH + k];
        out[(size_t)g * CC + f] = s;
    }
}

extern "C" void kernel_launch(void* const* d_in, const int* in_sizes, int n_in,
                              void* d_out, int out_size, void* d_ws, size_t ws_size,
                              hipStream_t stream)
{
    const float* x       = (const float*)d_in[0];
    const int*   ei      = (const int*)d_in[1];
    const int*   batch   = (const int*)d_in[2];
    const float* w1_rel  = (const float*)d_in[3];
    const float* w1_root = (const float*)d_in[4];
    const float* b1      = (const float*)d_in[5];
    const float* w2_rel  = (const float*)d_in[6];
    const float* w2_root = (const float*)d_in[7];
    const float* b2      = (const float*)d_in[8];
    const float* w3_rel  = (const float*)d_in[9];
    const float* w3_root = (const float*)d_in[10];
    const float* b3      = (const float*)d_in[11];
    const float* w4_rel  = (const float*)d_in[12];
    const float* w4_root = (const float*)d_in[13];
    const float* b4      = (const float*)d_in[14];
    const float* w5_rel  = (const float*)d_in[15];   // [128, 512]
    const float* w5_root = (const float*)d_in[16];   // [128, 512]
    const float* b5      = (const float*)d_in[17];
    const float* gamma   = (const float*)d_in[18];
    const float* beta    = (const float*)d_in[19];
    const float* lin_w   = (const float*)d_in[20];
    const float* lin_b   = (const float*)d_in[21];
    float* out = (float*)d_out;

    const size_t NH = (size_t)NN * HH;   // 2,560,000
    float*  XR  = (float*)d_ws;          // root GEMM out; becomes X5 in-place
    float*  T1  = XR + NH;               // rel GEMM out
    ushort* X1h = (ushort*)(T1 + NH);
    ushort* X1l = X1h + NH;
    ushort* X2h = X1l + NH;
    ushort* X2l = X2h + NH;
    ushort* X3h = X2l + NH;
    ushort* X3l = X3h + NH;
    ushort* X4h = X3l + NH;
    ushort* X4l = X4h + NH;
    const int K1P = 224;                 // 200 padded to 7*32
    ushort* W1h = X4l + NH;              // [256][224]
    ushort* W1l = W1h + 256 * K1P;
    ushort* W2h = W1l + 256 * K1P;       // [256][128] x3 layers
    ushort* W2l = W2h + 256 * 128;
    ushort* W3h = W2l + 256 * 128;
    ushort* W3l = W3h + 256 * 128;
    ushort* W4h = W3l + 256 * 128;
    ushort* W4l = W4h + 256 * 128;
    ushort* W5h = W4l + 256 * 128;       // [256][512]
    ushort* W5l = W5h + 256 * 512;
    float*  STATS = (float*)(W5l + 256 * 512);   // 256
    float*  POOL  = STATS + 256;                 // GG*HH
    int* row_ptr = (int*)(POOL + (size_t)GG * HH);  // NN+1
    int* pos     = row_ptr + (NN + 1);
    int* deg     = pos + NN;
    int* eidx    = deg + NN;
    const size_t need = (size_t)(eidx + EE) - (size_t)d_ws;
    if (ws_size < need) return;

    const dim3 blk(256);
    const int ggemm = (NN + 31) / 32;       // 625 blocks x 128 thr (gemm_mfma)
    const int ggw   = NN / RPB;             // 250 blocks x 512 thr (gemm_wreg)
    const int gedge = (EE + 255) / 256;
    const int ggath = (NN + 7) / 8;

    zero_k<<<(256 + GG * HH + 255) / 256, blk, 0, stream>>>(STATS, 256 + GG * HH);
    zero_k<<<(NN + 255) / 256, blk, 0, stream>>>((float*)deg, NN);

    // CSR build
    hist_k<<<gedge, blk, 0, stream>>>(ei, deg);
    scan_k<<<1, dim3(1024), 0, stream>>>(deg, row_ptr, pos);
    fill_k<<<gedge, blk, 0, stream>>>(ei, pos, eidx);

    // weight hi/lo splits
    split_w<<<(256 * K1P + 255) / 256, blk, 0, stream>>>(w1_root, w1_rel, FIN, K1P, W1h, W1l, 256 * K1P);
    split_w<<<(256 * 128 + 255) / 256, blk, 0, stream>>>(w2_root, w2_rel, HH, 128, W2h, W2l, 256 * 128);
    split_w<<<(256 * 128 + 255) / 256, blk, 0, stream>>>(w3_root, w3_rel, HH, 128, W3h, W3l, 256 * 128);
    split_w<<<(256 * 128 + 255) / 256, blk, 0, stream>>>(w4_root, w4_rel, HH, 128, W4h, W4l, 256 * 128);
    split_w<<<(256 * 512 + 255) / 256, blk, 0, stream>>>(w5_root, w5_rel, 512, 512, W5h, W5l, 256 * 512);

    const ushort* xu = (const ushort*)x;    // CVT path casts back to float*
    // layer 1: R6-proven kernel (fp32 x converted in-register, W padded 224)
    gemm_mfma<1, true ><<<ggemm, dim3(128), 0, stream>>>(xu, xu, xu, xu, xu, xu, xu, xu,
                                                         FIN, W1h, W1l, K1P, b1, XR, T1, NN);
    gather_hilo<<<ggath, blk, 0, stream>>>(XR, T1, row_ptr, eidx, X1h, X1l);
    // layers 2-4: W-in-registers streaming GEMM (col-index fixed)
    gemm_wreg<<<ggw, dim3(512), 0, stream>>>(X1h, X1l, W2h, W2l, b2, XR, T1);
    gather_hilo<<<ggath, blk, 0, stream>>>(XR, T1, row_ptr, eidx, X2h, X2l);
    gemm_wreg<<<ggw, dim3(512), 0, stream>>>(X2h, X2l, W3h, W3l, b3, XR, T1);
    gather_hilo<<<ggath, blk, 0, stream>>>(XR, T1, row_ptr, eidx, X3h, X3l);
    gemm_wreg<<<ggw, dim3(512), 0, stream>>>(X3h, X3l, W4h, W4l, b4, XR, T1);
    gather_hilo<<<ggath, blk, 0, stream>>>(XR, T1, row_ptr, eidx, X4h, X4l);
    // layer 5: R6-proven concat kernel (K=512 over 4 hi/lo sources)
    gemm_mfma<4, false><<<ggemm, dim3(128), 0, stream>>>(X1h, X1l, X2h, X2l, X3h, X3l, X4h, X4l,
                                                         HH, W5h, W5l, 512, b5, XR, T1, NN);
    gather_f32<<<ggath, blk, 0, stream>>>(T1, row_ptr, eidx, XR);   // X5 := XR in-place

    // BN stats, pooling, epilogue
    bn_stats<<<80, blk, 0, stream>>>(XR, STATS);
    pool_sum<<<(NN + 63) / 64, dim3(128), 0, stream>>>(XR, batch, POOL);
    finalize<<<GG, dim3(128), 0, stream>>>(STATS, POOL, batch, gamma, beta, lin_w, lin_b, out);
}

// Round 11
// 375.171 us; speedup vs baseline: 1.3719x; 1.1257x over previous
//
#include <hip/hip_runtime.h>

#define NN 20000
#define EE 320000
#define FIN 200
#define HH 128
#define CC 10
#define GG 100
#define BN_EPS 1e-5f
#define RPB 80          // rows per gemm block; 250 blocks x 80 = 20000

typedef __attribute__((ext_vector_type(8))) short bf16x8;
typedef __attribute__((ext_vector_type(4))) float f32x4;

__device__ __forceinline__ ushort bf16rn(float x) {
    uint u = __float_as_uint(x);
    u += 0x7FFFu + ((u >> 16) & 1u);
    return (ushort)(u >> 16);
}

// Fragment-major packing for [R][K] bf16 (K%32==0):
// elem (r,k) -> ((r>>4)*(K/32) + (k>>5))*512 + (((k>>3)&3)*16 + (r&15))*8 + (k&7)
// A wave's mfma fragment (rows r0..r0+15, k-block ks) is then lane l -> base + l*8
// ushorts: ONE fully-coalesced 1KB load (fixes the 16-line scatter that held
// every R6-R10 GEMM at a ~60us latency floor).

// ---------------------------------------------------------------------------
// Packed W-in-registers GEMM: Croot = A@Wroot^T (+bias), Crel = A@Wrel^T.
// Split-bf16: A*W = Ahi*Whi + Alo*Whi + Ahi*Wlo. Block 512 thr = 8 waves;
// wave w: matsel=w>>2, local cols ncol=(w&3)*32 (2 nf frags). W slice in VGPR
// loaded once (coalesced); streams RPB rows in 16-row chunks.
// ---------------------------------------------------------------------------
template<int KSTEPS>
__global__ __launch_bounds__(512)
void gemm_pk(const ushort* __restrict__ Aph, const ushort* __restrict__ Apl,
             const ushort* __restrict__ Wph, const ushort* __restrict__ Wpl,
             const float* __restrict__ bias,
             float* __restrict__ Croot, float* __restrict__ Crel)
{
    const int wid  = threadIdx.x >> 6;
    const int lane = threadIdx.x & 63;
    const int l15  = lane & 15;
    const int matsel = wid >> 2;
    const int ncol = (wid & 3) * 32;            // local col base (0..96)
    const int wrg0 = matsel * 8 + (ncol >> 4);  // row-group in combined W [256]
    const int rowb = (lane >> 4) * 4;
    const int rbase0 = blockIdx.x * RPB;

    bf16x8 wh[2][KSTEPS], wl[2][KSTEPS];
    #pragma unroll
    for (int nf = 0; nf < 2; ++nf) {
        const size_t wbase = (size_t)(wrg0 + nf) * KSTEPS * 512;
        #pragma unroll
        for (int ks = 0; ks < KSTEPS; ++ks) {
            wh[nf][ks] = *(const bf16x8*)&Wph[wbase + (size_t)(ks * 64 + lane) * 8];
            wl[nf][ks] = *(const bf16x8*)&Wpl[wbase + (size_t)(ks * 64 + lane) * 8];
        }
    }
    float bv[2] = {0.f, 0.f};
    if (matsel == 0 && bias) { bv[0] = bias[ncol + l15]; bv[1] = bias[ncol + 16 + l15]; }
    float* __restrict__ C = matsel ? Crel : Croot;

    for (int ch = 0; ch < RPB; ch += 16) {
        const size_t abase = (size_t)((rbase0 + ch) >> 4) * KSTEPS * 512;
        f32x4 acc[2] = {};
        #pragma unroll
        for (int ks = 0; ks < KSTEPS; ++ks) {
            const bf16x8 ah = *(const bf16x8*)&Aph[abase + (size_t)(ks * 64 + lane) * 8];
            const bf16x8 al = *(const bf16x8*)&Apl[abase + (size_t)(ks * 64 + lane) * 8];
            #pragma unroll
            for (int nf = 0; nf < 2; ++nf) {
                acc[nf] = __builtin_amdgcn_mfma_f32_16x16x32_bf16(ah, wh[nf][ks], acc[nf], 0, 0, 0);
                acc[nf] = __builtin_amdgcn_mfma_f32_16x16x32_bf16(al, wh[nf][ks], acc[nf], 0, 0, 0);
                acc[nf] = __builtin_amdgcn_mfma_f32_16x16x32_bf16(ah, wl[nf][ks], acc[nf], 0, 0, 0);
            }
        }
        #pragma unroll
        for (int nf = 0; nf < 2; ++nf) {
            const int col = ncol + nf * 16 + l15;   // LOCAL column (0..127)
            #pragma unroll
            for (int j = 0; j < 4; ++j) {
                const int row = rbase0 + ch + rowb + j;
                C[(size_t)row * HH + col] = acc[nf][j] + bv[nf];
            }
        }
    }
}

// ---------------------------------------------------------------------------
// Layer-5 packed concat-GEMM: K=512 over 4 packed sources (KSTEPS=4 each).
// src loop OUTER (W regs reloaded per src), persistent acc[5][2], C once.
// ---------------------------------------------------------------------------
__global__ __launch_bounds__(512)
void gemm_pk4(const ushort* __restrict__ X1h, const ushort* __restrict__ X1l,
              const ushort* __restrict__ X2h, const ushort* __restrict__ X2l,
              const ushort* __restrict__ X3h, const ushort* __restrict__ X3l,
              const ushort* __restrict__ X4h, const ushort* __restrict__ X4l,
              const ushort* __restrict__ Wph, const ushort* __restrict__ Wpl,
              const float* __restrict__ bias,
              float* __restrict__ Croot, float* __restrict__ Crel)
{
    const int wid  = threadIdx.x >> 6;
    const int lane = threadIdx.x & 63;
    const int l15  = lane & 15;
    const int matsel = wid >> 2;
    const int ncol = (wid & 3) * 32;
    const int wrg0 = matsel * 8 + (ncol >> 4);
    const int rowb = (lane >> 4) * 4;
    const int rbase0 = blockIdx.x * RPB;
    const ushort* const Ahs[4] = {X1h, X2h, X3h, X4h};
    const ushort* const Als[4] = {X1l, X2l, X3l, X4l};

    f32x4 acc[5][2] = {};
    #pragma unroll
    for (int src = 0; src < 4; ++src) {
        const ushort* __restrict__ Ah_ = Ahs[src];
        const ushort* __restrict__ Al_ = Als[src];
        bf16x8 wh[2][4], wl[2][4];
        #pragma unroll
        for (int nf = 0; nf < 2; ++nf) {
            // combined-W row-group (wrg0+nf), global kstep = src*4 + ks (16 total)
            const size_t wbase = ((size_t)(wrg0 + nf) * 16 + src * 4) * 512;
            #pragma unroll
            for (int ks = 0; ks < 4; ++ks) {
                wh[nf][ks] = *(const bf16x8*)&Wph[wbase + (size_t)(ks * 64 + lane) * 8];
                wl[nf][ks] = *(const bf16x8*)&Wpl[wbase + (size_t)(ks * 64 + lane) * 8];
            }
        }
        #pragma unroll
        for (int ch = 0; ch < 5; ++ch) {
            const size_t abase = (size_t)((rbase0 + ch * 16) >> 4) * 4 * 512;
            #pragma unroll
            for (int ks = 0; ks < 4; ++ks) {
                const bf16x8 ah = *(const bf16x8*)&Ah_[abase + (size_t)(ks * 64 + lane) * 8];
                const bf16x8 al = *(const bf16x8*)&Al_[abase + (size_t)(ks * 64 + lane) * 8];
                #pragma unroll
                for (int nf = 0; nf < 2; ++nf) {
                    acc[ch][nf] = __builtin_amdgcn_mfma_f32_16x16x32_bf16(ah, wh[nf][ks], acc[ch][nf], 0, 0, 0);
                    acc[ch][nf] = __builtin_amdgcn_mfma_f32_16x16x32_bf16(al, wh[nf][ks], acc[ch][nf], 0, 0, 0);
                    acc[ch][nf] = __builtin_amdgcn_mfma_f32_16x16x32_bf16(ah, wl[nf][ks], acc[ch][nf], 0, 0, 0);
                }
            }
        }
    }
    float bv[2] = {0.f, 0.f};
    if (matsel == 0 && bias) { bv[0] = bias[ncol + l15]; bv[1] = bias[ncol + 16 + l15]; }
    float* __restrict__ C = matsel ? Crel : Croot;
    #pragma unroll
    for (int ch = 0; ch < 5; ++ch) {
        #pragma unroll
        for (int nf = 0; nf < 2; ++nf) {
            const int col = ncol + nf * 16 + l15;   // LOCAL column
            #pragma unroll
            for (int j = 0; j < 4; ++j) {
                const int row = rbase0 + ch * 16 + rowb + j;
                C[(size_t)row * HH + col] = acc[ch][nf][j] + bv[nf];
            }
        }
    }
}

// ---------------------------------------------------------------------------
// weight split into fragment-packed hi/lo: combined [256][Kp] from root+rel
// ---------------------------------------------------------------------------
__global__ void split_w(const float* __restrict__ Wroot, const float* __restrict__ Wrel,
                        int K, int Kp, ushort* __restrict__ Wh, ushort* __restrict__ Wl,
                        int total)
{
    int i = blockIdx.x * blockDim.x + threadIdx.x;
    if (i >= total) return;
    const int row = i / Kp, col = i - row * Kp;
    float v = 0.f;
    if (col < K) v = (row < 128) ? Wroot[row * K + col] : Wrel[(row - 128) * K + col];
    const ushort h = bf16rn(v);
    const float hf = __uint_as_float((uint)h << 16);
    const int ksteps = Kp >> 5;
    const size_t addr = ((size_t)(row >> 4) * ksteps + (col >> 5)) * 512
                      + (size_t)(((col >> 3) & 3) * 16 + (row & 15)) * 8 + (col & 7);
    Wh[addr] = h;
    Wl[addr] = bf16rn(v - hf);
}

// ---------------------------------------------------------------------------
// pack layer-1 input: x [20000][200] fp32 -> packed hi/lo, K padded to 224.
// block 448 thr = 16 nodes x 28 octets; packed writes coalesce (16B/thread runs)
// ---------------------------------------------------------------------------
__global__ __launch_bounds__(448)
void pack_x(const float* __restrict__ x, ushort* __restrict__ Xh, ushort* __restrict__ Xl)
{
    const int t = threadIdx.x;
    const int n = blockIdx.x * 16 + (t & 15);
    const int o = t >> 4;                   // k-octet 0..27 (k = o*8)
    float v[8];
    if (o < 25) {                           // o=24 -> k 192..199, all < 200
        const float4 a = *(const float4*)&x[(size_t)n * FIN + o * 8];
        const float4 b = *(const float4*)&x[(size_t)n * FIN + o * 8 + 4];
        v[0]=a.x; v[1]=a.y; v[2]=a.z; v[3]=a.w; v[4]=b.x; v[5]=b.y; v[6]=b.z; v[7]=b.w;
    } else {
        #pragma unroll
        for (int j = 0; j < 8; ++j) v[j] = 0.f;
    }
    bf16x8 h, l;
    #pragma unroll
    for (int j = 0; j < 8; ++j) {
        const ushort hh = bf16rn(v[j]);
        h[j] = (short)hh;
        l[j] = (short)bf16rn(v[j] - __uint_as_float((uint)hh << 16));
    }
    const size_t addr = ((size_t)(n >> 4) * 7 + (o >> 2)) * 512
                      + (size_t)((o & 3) * 16 + (n & 15)) * 8;
    *(bf16x8*)&Xh[addr] = h;
    *(bf16x8*)&Xl[addr] = l;
}

// ---------------------------------------------------------------------------
// CSR build
// ---------------------------------------------------------------------------
__global__ void hist_k(const int* __restrict__ ei, int* __restrict__ deg)
{
    int e = blockIdx.x * blockDim.x + threadIdx.x;
    if (e < EE) atomicAdd(&deg[ei[EE + e]], 1);
}

__global__ __launch_bounds__(1024)
void scan_k(const int* __restrict__ deg, int* __restrict__ row_ptr,
            int* __restrict__ pos)
{
    __shared__ int part[1024];
    const int t = threadIdx.x;
    const int chunk = (NN + 1023) / 1024;
    const int i0 = t * chunk;
    const int i1 = min(i0 + chunk, NN);
    int s = 0;
    for (int i = i0; i < i1; ++i) s += deg[i];
    part[t] = s;
    __syncthreads();
    for (int off = 1; off < 1024; off <<= 1) {
        int v = (t >= off) ? part[t - off] : 0;
        __syncthreads();
        part[t] += v;
        __syncthreads();
    }
    int run = (t == 0) ? 0 : part[t - 1];
    for (int i = i0; i < i1; ++i) {
        const int d = deg[i];
        row_ptr[i] = run;
        pos[i] = run;
        run += d;
    }
    if (t == 0) row_ptr[NN] = part[1023];
}

__global__ void fill_k(const int* __restrict__ ei, int* __restrict__ pos,
                       int* __restrict__ eidx)
{
    int e = blockIdx.x * blockDim.x + threadIdx.x;
    if (e < EE) {
        const int slot = atomicAdd(&pos[ei[EE + e]], 1);
        eidx[slot] = ei[e];
    }
}

// ---------------------------------------------------------------------------
// gather + ReLU + hi/lo split -> fragment-packed output.
// block 256 thr = 16 nodes x 16 k-octets; thread (n,o) owns 8 k-values.
// t -> o = ((t>>6)<<2) | ((t>>4)&3), n = n0 + (t&15): packed store offset is
// exactly t*16B -> block writes one contiguous 4KB run per buffer.
// ---------------------------------------------------------------------------
__global__ __launch_bounds__(256)
void gather_pk(const float* __restrict__ base, const float* __restrict__ T1,
               const int* __restrict__ row_ptr, const int* __restrict__ eidx,
               ushort* __restrict__ Xh, ushort* __restrict__ Xl)
{
    const int t  = threadIdx.x;
    const int nl = t & 15;
    const int n  = blockIdx.x * 16 + nl;
    const int o  = ((t >> 6) << 2) | ((t >> 4) & 3);   // 0..15
    const int e0 = row_ptr[n], e1 = row_ptr[n + 1];
    float4 p0 = *(const float4*)&base[(size_t)n * HH + o * 8];
    float4 p1 = *(const float4*)&base[(size_t)n * HH + o * 8 + 4];
    float4 q0 = {0,0,0,0}, q1 = {0,0,0,0};
    int e = e0;
    for (; e + 2 <= e1; e += 2) {
        const int s0 = eidx[e], s1 = eidx[e + 1];
        const float4 a0 = *(const float4*)&T1[(size_t)s0 * HH + o * 8];
        const float4 a1 = *(const float4*)&T1[(size_t)s0 * HH + o * 8 + 4];
        const float4 b0 = *(const float4*)&T1[(size_t)s1 * HH + o * 8];
        const float4 b1 = *(const float4*)&T1[(size_t)s1 * HH + o * 8 + 4];
        p0.x += a0.x; p0.y += a0.y; p0.z += a0.z; p0.w += a0.w;
        p1.x += a1.x; p1.y += a1.y; p1.z += a1.z; p1.w += a1.w;
        q0.x += b0.x; q0.y += b0.y; q0.z += b0.z; q0.w += b0.w;
        q1.x += b1.x; q1.y += b1.y; q1.z += b1.z; q1.w += b1.w;
    }
    if (e < e1) {
        const int s = eidx[e];
        const float4 a0 = *(const float4*)&T1[(size_t)s * HH + o * 8];
        const float4 a1 = *(const float4*)&T1[(size_t)s * HH + o * 8 + 4];
        p0.x += a0.x; p0.y += a0.y; p0.z += a0.z; p0.w += a0.w;
        p1.x += a1.x; p1.y += a1.y; p1.z += a1.z; p1.w += a1.w;
    }
    float v[8];
    v[0] = fmaxf(p0.x + q0.x, 0.f); v[1] = fmaxf(p0.y + q0.y, 0.f);
    v[2] = fmaxf(p0.z + q0.z, 0.f); v[3] = fmaxf(p0.w + q0.w, 0.f);
    v[4] = fmaxf(p1.x + q1.x, 0.f); v[5] = fmaxf(p1.y + q1.y, 0.f);
    v[6] = fmaxf(p1.z + q1.z, 0.f); v[7] = fmaxf(p1.w + q1.w, 0.f);
    bf16x8 h, l;
    #pragma unroll
    for (int j = 0; j < 8; ++j) {
        const ushort hh = bf16rn(v[j]);
        h[j] = (short)hh;
        l[j] = (short)bf16rn(v[j] - __uint_as_float((uint)hh << 16));
    }
    const size_t addr = ((size_t)(n >> 4) * 4 + (o >> 2)) * 512
                      + (size_t)((o & 3) * 16 + nl) * 8;
    *(bf16x8*)&Xh[addr] = h;
    *(bf16x8*)&Xl[addr] = l;
}

// gather for layer 5: fp32, in-place on base (linear), no relu
__global__ __launch_bounds__(256)
void gather_f32(const float* __restrict__ T1, const int* __restrict__ row_ptr,
                const int* __restrict__ eidx, float* __restrict__ X)
{
    const int n  = blockIdx.x * 8 + (threadIdx.x >> 5);
    const int f4 = threadIdx.x & 31;
    if (n >= NN) return;
    const int e0 = row_ptr[n], e1 = row_ptr[n + 1];
    float4 a0 = *(const float4*)&X[(size_t)n * HH + f4 * 4];
    float4 a1 = {0,0,0,0}, a2 = {0,0,0,0}, a3 = {0,0,0,0};
    int e = e0;
    for (; e + 4 <= e1; e += 4) {
        const int s0 = eidx[e], s1 = eidx[e+1], s2 = eidx[e+2], s3 = eidx[e+3];
        const float4 v0 = *(const float4*)&T1[(size_t)s0 * HH + f4 * 4];
        const float4 v1 = *(const float4*)&T1[(size_t)s1 * HH + f4 * 4];
        const float4 v2 = *(const float4*)&T1[(size_t)s2 * HH + f4 * 4];
        const float4 v3 = *(const float4*)&T1[(size_t)s3 * HH + f4 * 4];
        a0.x += v0.x; a0.y += v0.y; a0.z += v0.z; a0.w += v0.w;
        a1.x += v1.x; a1.y += v1.y; a1.z += v1.z; a1.w += v1.w;
        a2.x += v2.x; a2.y += v2.y; a2.z += v2.z; a2.w += v2.w;
        a3.x += v3.x; a3.y += v3.y; a3.z += v3.z; a3.w += v3.w;
    }
    for (; e < e1; ++e) {
        const int s = eidx[e];
        const float4 v = *(const float4*)&T1[(size_t)s * HH + f4 * 4];
        a0.x += v.x; a0.y += v.y; a0.z += v.z; a0.w += v.w;
    }
    float4 acc;
    acc.x = (a0.x + a1.x) + (a2.x + a3.x);
    acc.y = (a0.y + a1.y) + (a2.y + a3.y);
    acc.z = (a0.z + a1.z) + (a2.z + a3.z);
    acc.w = (a0.w + a1.w) + (a2.w + a3.w);
    *(float4*)&X[(size_t)n * HH + f4 * 4] = acc;
}

__global__ void zero_k(float* __restrict__ p, int n)
{
    int i = blockIdx.x * blockDim.x + threadIdx.x;
    if (i < n) p[i] = 0.f;
}

__global__ __launch_bounds__(256)
void bn_stats(const float* __restrict__ x5, float* __restrict__ stats)
{
    __shared__ float sh_s[256], sh_q[256];
    const int f    = threadIdx.x & 127;
    const int half = threadIdx.x >> 7;
    const int rpb  = (NN + gridDim.x - 1) / gridDim.x;
    const int r0   = blockIdx.x * rpb;
    const int r1   = min(r0 + rpb, NN);
    float s = 0.f, q = 0.f;
    for (int r = r0 + half; r < r1; r += 2) {
        const float v = x5[(size_t)r * HH + f];
        s += v; q += v * v;
    }
    sh_s[threadIdx.x] = s; sh_q[threadIdx.x] = q;
    __syncthreads();
    if (half == 0) {
        s += sh_s[128 + f]; q += sh_q[128 + f];
        atomicAdd(&stats[f], s);
        atomicAdd(&stats[128 + f], q);
    }
}

__global__ __launch_bounds__(128)
void pool_sum(const float* __restrict__ x5, const int* __restrict__ batch,
              float* __restrict__ pool)
{
    const int f  = threadIdx.x;
    const int n0 = blockIdx.x * 64;
    const int n1 = min(n0 + 64, NN);
    float acc = 0.f;
    int curg = batch[n0];
    for (int n = n0; n < n1; ++n) {
        const int g = batch[n];
        if (g != curg) {
            atomicAdd(&pool[(size_t)curg * HH + f], acc);
            acc = 0.f; curg = g;
        }
        acc += x5[(size_t)n * HH + f];
    }
    atomicAdd(&pool[(size_t)curg * HH + f], acc);
}

__global__ __launch_bounds__(128)
void finalize(const float* __restrict__ stats, const float* __restrict__ pool,
              const int* __restrict__ batch,
              const float* __restrict__ gamma, const float* __restrict__ beta,
              const float* __restrict__ lin_w, const float* __restrict__ lin_b,
              float* __restrict__ out)
{
    const int g = blockIdx.x, f = threadIdx.x;
    __shared__ int seg[2];
    if (f < 2) {
        const int target = g + f;
        int lo = 0, hi = NN;
        while (lo < hi) {
            const int mid = (lo + hi) >> 1;
            if (batch[mid] < target) lo = mid + 1; else hi = mid;
        }
        seg[f] = lo;
    }
    __syncthreads();
    const float c   = (float)(seg[1] - seg[0]);
    const float mu  = stats[f] * (1.0f / NN);
    const float var = stats[128 + f] * (1.0f / NN) - mu * mu;
    const float scale = gamma[f] * rsqrtf(var + BN_EPS);
    const float pm = pool[(size_t)g * HH + f] / fmaxf(c, 1.0f);
    __shared__ float sh[128];
    sh[f] = (pm - mu) * scale + beta[f];
    __syncthreads();
    if (f < CC) {
        float s = lin_b[f];
        #pragma unroll 8
        for (int k = 0; k < HH; ++k) s += sh[k] * lin_w[f * HH + k];
        out[(size_t)g * CC + f] = s;
    }
}

extern "C" void kernel_launch(void* const* d_in, const int* in_sizes, int n_in,
                              void* d_out, int out_size, void* d_ws, size_t ws_size,
                              hipStream_t stream)
{
    const float* x       = (const float*)d_in[0];
    const int*   ei      = (const int*)d_in[1];
    const int*   batch   = (const int*)d_in[2];
    const float* w1_rel  = (const float*)d_in[3];
    const float* w1_root = (const float*)d_in[4];
    const float* b1      = (const float*)d_in[5];
    const float* w2_rel  = (const float*)d_in[6];
    const float* w2_root = (const float*)d_in[7];
    const float* b2      = (const float*)d_in[8];
    const float* w3_rel  = (const float*)d_in[9];
    const float* w3_root = (const float*)d_in[10];
    const float* b3      = (const float*)d_in[11];
    const float* w4_rel  = (const float*)d_in[12];
    const float* w4_root = (const float*)d_in[13];
    const float* b4      = (const float*)d_in[14];
    const float* w5_rel  = (const float*)d_in[15];   // [128, 512]
    const float* w5_root = (const float*)d_in[16];   // [128, 512]
    const float* b5      = (const float*)d_in[17];
    const float* gamma   = (const float*)d_in[18];
    const float* beta    = (const float*)d_in[19];
    const float* lin_w   = (const float*)d_in[20];
    const float* lin_b   = (const float*)d_in[21];
    float* out = (float*)d_out;

    const size_t NH = (size_t)NN * HH;   // 2,560,000
    float*  XR  = (float*)d_ws;          // root GEMM out; becomes X5 in-place
    float*  T1  = XR + NH;               // rel GEMM out
    ushort* X1h = (ushort*)(T1 + NH);    // packed per-layer activations
    ushort* X1l = X1h + NH;
    ushort* X2h = X1l + NH;
    ushort* X2l = X2h + NH;
    ushort* X3h = X2l + NH;
    ushort* X3l = X3h + NH;
    ushort* X4h = X3l + NH;
    ushort* X4l = X4h + NH;
    const int K1P = 224;                 // 200 padded to 7*32
    ushort* W1h = X4l + NH;              // packed combined [256][K1P]
    ushort* W1l = W1h + 256 * K1P;
    ushort* W2h = W1l + 256 * K1P;       // packed [256][128] x3
    ushort* W2l = W2h + 256 * 128;
    ushort* W3h = W2l + 256 * 128;
    ushort* W3l = W3h + 256 * 128;
    ushort* W4h = W3l + 256 * 128;
    ushort* W4l = W4h + 256 * 128;
    ushort* W5h = W4l + 256 * 128;       // packed [256][512]
    ushort* W5l = W5h + 256 * 512;
    float*  STATS = (float*)(W5l + 256 * 512);   // 256
    float*  POOL  = STATS + 256;                 // GG*HH
    int* row_ptr = (int*)(POOL + (size_t)GG * HH);  // NN+1
    int* pos     = row_ptr + (NN + 1);
    int* deg     = pos + NN;
    int* eidx    = deg + NN;
    const size_t need = (size_t)(eidx + EE) - (size_t)d_ws;
    if (ws_size < need) return;

    // packed layer-1 input aliases X2h..X3l (dead once L1 GEMM completes,
    // which happens before gather_pk writes X2)
    ushort* XPh = X2h;                       // 20000*224 ushorts
    ushort* XPl = X2h + (size_t)NN * K1P;

    const dim3 blk(256);
    const int ggw   = NN / RPB;             // 250 blocks x 512 thr
    const int gedge = (EE + 255) / 256;
    const int ggpk  = NN / 16;              // 1250 blocks (gather_pk, pack_x)
    const int ggath = (NN + 7) / 8;         // gather_f32

    zero_k<<<(256 + GG * HH + 255) / 256, blk, 0, stream>>>(STATS, 256 + GG * HH);
    zero_k<<<(NN + 255) / 256, blk, 0, stream>>>((float*)deg, NN);

    // CSR build
    hist_k<<<gedge, blk, 0, stream>>>(ei, deg);
    scan_k<<<1, dim3(1024), 0, stream>>>(deg, row_ptr, pos);
    fill_k<<<gedge, blk, 0, stream>>>(ei, pos, eidx);

    // weight splits (fragment-packed) + layer-1 input pack
    split_w<<<(256 * K1P + 255) / 256, blk, 0, stream>>>(w1_root, w1_rel, FIN, K1P, W1h, W1l, 256 * K1P);
    split_w<<<(256 * 128 + 255) / 256, blk, 0, stream>>>(w2_root, w2_rel, HH, 128, W2h, W2l, 256 * 128);
    split_w<<<(256 * 128 + 255) / 256, blk, 0, stream>>>(w3_root, w3_rel, HH, 128, W3h, W3l, 256 * 128);
    split_w<<<(256 * 128 + 255) / 256, blk, 0, stream>>>(w4_root, w4_rel, HH, 128, W4h, W4l, 256 * 128);
    split_w<<<(256 * 512 + 255) / 256, blk, 0, stream>>>(w5_root, w5_rel, 512, 512, W5h, W5l, 256 * 512);
    pack_x<<<ggpk, dim3(448), 0, stream>>>(x, XPh, XPl);

    // layer 1 (K=224 packed)
    gemm_pk<7><<<ggw, dim3(512), 0, stream>>>(XPh, XPl, W1h, W1l, b1, XR, T1);
    gather_pk<<<ggpk, blk, 0, stream>>>(XR, T1, row_ptr, eidx, X1h, X1l);
    // layers 2-4 (K=128 packed)
    gemm_pk<4><<<ggw, dim3(512), 0, stream>>>(X1h, X1l, W2h, W2l, b2, XR, T1);
    gather_pk<<<ggpk, blk, 0, stream>>>(XR, T1, row_ptr, eidx, X2h, X2l);
    gemm_pk<4><<<ggw, dim3(512), 0, stream>>>(X2h, X2l, W3h, W3l, b3, XR, T1);
    gather_pk<<<ggpk, blk, 0, stream>>>(XR, T1, row_ptr, eidx, X3h, X3l);
    gemm_pk<4><<<ggw, dim3(512), 0, stream>>>(X3h, X3l, W4h, W4l, b4, XR, T1);
    gather_pk<<<ggpk, blk, 0, stream>>>(XR, T1, row_ptr, eidx, X4h, X4l);
    // layer 5: packed concat over X1..X4, K=512, single dispatch
    gemm_pk4<<<ggw, dim3(512), 0, stream>>>(X1h, X1l, X2h, X2l, X3h, X3l, X4h, X4l,
                                            W5h, W5l, b5, XR, T1);
    gather_f32<<<ggath, blk, 0, stream>>>(T1, row_ptr, eidx, XR);   // X5 := XR in-place

    // BN stats, pooling, epilogue
    bn_stats<<<80, blk, 0, stream>>>(XR, STATS);
    pool_sum<<<(NN + 63) / 64, dim3(128), 0, stream>>>(XR, batch, POOL);
    finalize<<<GG, dim3(128), 0, stream>>>(STATS, POOL, batch, gamma, beta, lin_w, lin_b, out);
}

// Round 12
// 355.368 us; speedup vs baseline: 1.4483x; 1.0557x over previous
//
#include <hip/hip_runtime.h>

#define NN 20000
#define EE 320000
#define FIN 200
#define HH 128
#define CC 10
#define GG 100
#define BN_EPS 1e-5f
#define RPB 80          // rows per gemm block; 250 blocks x 80 = 20000

typedef __attribute__((ext_vector_type(8))) short bf16x8;
typedef __attribute__((ext_vector_type(4))) float f32x4;

__device__ __forceinline__ ushort bf16rn(float x) {
    uint u = __float_as_uint(x);
    u += 0x7FFFu + ((u >> 16) & 1u);
    return (ushort)(u >> 16);
}

// Fragment-major packing for [R][K] bf16 (K%32==0):
// elem (r,k) -> ((r>>4)*(K/32) + (k>>5))*512 + (((k>>3)&3)*16 + (r&15))*8 + (k&7)
// A wave's mfma fragment load is then lane l -> base + l*16B: one coalesced 1KB.

// ---------------------------------------------------------------------------
// Packed W-in-registers GEMM (verified R11): Croot = A@Wroot^T (+bias),
// Crel = A@Wrel^T. Split-bf16: A*W = Ahi*Whi + Alo*Whi + Ahi*Wlo.
// Block 512 thr = 8 waves; wave w: matsel=w>>2, ncol=(w&3)*32 (2 nf frags).
// ---------------------------------------------------------------------------
template<int KSTEPS>
__global__ __launch_bounds__(512)
void gemm_pk(const ushort* __restrict__ Aph, const ushort* __restrict__ Apl,
             const ushort* __restrict__ Wph, const ushort* __restrict__ Wpl,
             const float* __restrict__ bias,
             float* __restrict__ Croot, float* __restrict__ Crel)
{
    const int wid  = threadIdx.x >> 6;
    const int lane = threadIdx.x & 63;
    const int l15  = lane & 15;
    const int matsel = wid >> 2;
    const int ncol = (wid & 3) * 32;            // local col base (0..96)
    const int wrg0 = matsel * 8 + (ncol >> 4);  // row-group in combined W [256]
    const int rowb = (lane >> 4) * 4;
    const int rbase0 = blockIdx.x * RPB;

    bf16x8 wh[2][KSTEPS], wl[2][KSTEPS];
    #pragma unroll
    for (int nf = 0; nf < 2; ++nf) {
        const size_t wbase = (size_t)(wrg0 + nf) * KSTEPS * 512;
        #pragma unroll
        for (int ks = 0; ks < KSTEPS; ++ks) {
            wh[nf][ks] = *(const bf16x8*)&Wph[wbase + (size_t)(ks * 64 + lane) * 8];
            wl[nf][ks] = *(const bf16x8*)&Wpl[wbase + (size_t)(ks * 64 + lane) * 8];
        }
    }
    float bv[2] = {0.f, 0.f};
    if (matsel == 0 && bias) { bv[0] = bias[ncol + l15]; bv[1] = bias[ncol + 16 + l15]; }
    float* __restrict__ C = matsel ? Crel : Croot;

    for (int ch = 0; ch < RPB; ch += 16) {
        const size_t abase = (size_t)((rbase0 + ch) >> 4) * KSTEPS * 512;
        f32x4 acc[2] = {};
        #pragma unroll
        for (int ks = 0; ks < KSTEPS; ++ks) {
            const bf16x8 ah = *(const bf16x8*)&Aph[abase + (size_t)(ks * 64 + lane) * 8];
            const bf16x8 al = *(const bf16x8*)&Apl[abase + (size_t)(ks * 64 + lane) * 8];
            #pragma unroll
            for (int nf = 0; nf < 2; ++nf) {
                acc[nf] = __builtin_amdgcn_mfma_f32_16x16x32_bf16(ah, wh[nf][ks], acc[nf], 0, 0, 0);
                acc[nf] = __builtin_amdgcn_mfma_f32_16x16x32_bf16(al, wh[nf][ks], acc[nf], 0, 0, 0);
                acc[nf] = __builtin_amdgcn_mfma_f32_16x16x32_bf16(ah, wl[nf][ks], acc[nf], 0, 0, 0);
            }
        }
        #pragma unroll
        for (int nf = 0; nf < 2; ++nf) {
            const int col = ncol + nf * 16 + l15;   // LOCAL column (0..127)
            #pragma unroll
            for (int j = 0; j < 4; ++j) {
                const int row = rbase0 + ch + rowb + j;
                C[(size_t)row * HH + col] = acc[nf][j] + bv[nf];
            }
        }
    }
}

// ---------------------------------------------------------------------------
// Layer-5 packed concat-GEMM (verified R11): K=512 over 4 packed sources.
// ---------------------------------------------------------------------------
__global__ __launch_bounds__(512)
void gemm_pk4(const ushort* __restrict__ X1h, const ushort* __restrict__ X1l,
              const ushort* __restrict__ X2h, const ushort* __restrict__ X2l,
              const ushort* __restrict__ X3h, const ushort* __restrict__ X3l,
              const ushort* __restrict__ X4h, const ushort* __restrict__ X4l,
              const ushort* __restrict__ Wph, const ushort* __restrict__ Wpl,
              const float* __restrict__ bias,
              float* __restrict__ Croot, float* __restrict__ Crel)
{
    const int wid  = threadIdx.x >> 6;
    const int lane = threadIdx.x & 63;
    const int l15  = lane & 15;
    const int matsel = wid >> 2;
    const int ncol = (wid & 3) * 32;
    const int wrg0 = matsel * 8 + (ncol >> 4);
    const int rowb = (lane >> 4) * 4;
    const int rbase0 = blockIdx.x * RPB;
    const ushort* const Ahs[4] = {X1h, X2h, X3h, X4h};
    const ushort* const Als[4] = {X1l, X2l, X3l, X4l};

    f32x4 acc[5][2] = {};
    #pragma unroll
    for (int src = 0; src < 4; ++src) {
        const ushort* __restrict__ Ah_ = Ahs[src];
        const ushort* __restrict__ Al_ = Als[src];
        bf16x8 wh[2][4], wl[2][4];
        #pragma unroll
        for (int nf = 0; nf < 2; ++nf) {
            const size_t wbase = ((size_t)(wrg0 + nf) * 16 + src * 4) * 512;
            #pragma unroll
            for (int ks = 0; ks < 4; ++ks) {
                wh[nf][ks] = *(const bf16x8*)&Wph[wbase + (size_t)(ks * 64 + lane) * 8];
                wl[nf][ks] = *(const bf16x8*)&Wpl[wbase + (size_t)(ks * 64 + lane) * 8];
            }
        }
        #pragma unroll
        for (int ch = 0; ch < 5; ++ch) {
            const size_t abase = (size_t)((rbase0 + ch * 16) >> 4) * 4 * 512;
            #pragma unroll
            for (int ks = 0; ks < 4; ++ks) {
                const bf16x8 ah = *(const bf16x8*)&Ah_[abase + (size_t)(ks * 64 + lane) * 8];
                const bf16x8 al = *(const bf16x8*)&Al_[abase + (size_t)(ks * 64 + lane) * 8];
                #pragma unroll
                for (int nf = 0; nf < 2; ++nf) {
                    acc[ch][nf] = __builtin_amdgcn_mfma_f32_16x16x32_bf16(ah, wh[nf][ks], acc[ch][nf], 0, 0, 0);
                    acc[ch][nf] = __builtin_amdgcn_mfma_f32_16x16x32_bf16(al, wh[nf][ks], acc[ch][nf], 0, 0, 0);
                    acc[ch][nf] = __builtin_amdgcn_mfma_f32_16x16x32_bf16(ah, wl[nf][ks], acc[ch][nf], 0, 0, 0);
                }
            }
        }
    }
    float bv[2] = {0.f, 0.f};
    if (matsel == 0 && bias) { bv[0] = bias[ncol + l15]; bv[1] = bias[ncol + 16 + l15]; }
    float* __restrict__ C = matsel ? Crel : Croot;
    #pragma unroll
    for (int ch = 0; ch < 5; ++ch) {
        #pragma unroll
        for (int nf = 0; nf < 2; ++nf) {
            const int col = ncol + nf * 16 + l15;
            #pragma unroll
            for (int j = 0; j < 4; ++j) {
                const int row = rbase0 + ch * 16 + rowb + j;
                C[(size_t)row * HH + col] = acc[ch][nf][j] + bv[nf];
            }
        }
    }
}

// ---------------------------------------------------------------------------
// weight split into fragment-packed hi/lo: combined [256][Kp] from root+rel
// ---------------------------------------------------------------------------
__global__ void split_w(const float* __restrict__ Wroot, const float* __restrict__ Wrel,
                        int K, int Kp, ushort* __restrict__ Wh, ushort* __restrict__ Wl,
                        int total)
{
    int i = blockIdx.x * blockDim.x + threadIdx.x;
    if (i >= total) return;
    const int row = i / Kp, col = i - row * Kp;
    float v = 0.f;
    if (col < K) v = (row < 128) ? Wroot[row * K + col] : Wrel[(row - 128) * K + col];
    const ushort h = bf16rn(v);
    const float hf = __uint_as_float((uint)h << 16);
    const int ksteps = Kp >> 5;
    const size_t addr = ((size_t)(row >> 4) * ksteps + (col >> 5)) * 512
                      + (size_t)(((col >> 3) & 3) * 16 + (row & 15)) * 8 + (col & 7);
    Wh[addr] = h;
    Wl[addr] = bf16rn(v - hf);
}

// ---------------------------------------------------------------------------
// pack layer-1 input: x [20000][200] fp32 -> packed hi/lo, K padded to 224.
// ---------------------------------------------------------------------------
__global__ __launch_bounds__(448)
void pack_x(const float* __restrict__ x, ushort* __restrict__ Xh, ushort* __restrict__ Xl)
{
    const int t = threadIdx.x;
    const int n = blockIdx.x * 16 + (t & 15);
    const int o = t >> 4;                   // k-octet 0..27
    float v[8];
    if (o < 25) {
        const float4 a = *(const float4*)&x[(size_t)n * FIN + o * 8];
        const float4 b = *(const float4*)&x[(size_t)n * FIN + o * 8 + 4];
        v[0]=a.x; v[1]=a.y; v[2]=a.z; v[3]=a.w; v[4]=b.x; v[5]=b.y; v[6]=b.z; v[7]=b.w;
    } else {
        #pragma unroll
        for (int j = 0; j < 8; ++j) v[j] = 0.f;
    }
    bf16x8 h, l;
    #pragma unroll
    for (int j = 0; j < 8; ++j) {
        const ushort hh = bf16rn(v[j]);
        h[j] = (short)hh;
        l[j] = (short)bf16rn(v[j] - __uint_as_float((uint)hh << 16));
    }
    const size_t addr = ((size_t)(n >> 4) * 7 + (o >> 2)) * 512
                      + (size_t)((o & 3) * 16 + (n & 15)) * 8;
    *(bf16x8*)&Xh[addr] = h;
    *(bf16x8*)&Xl[addr] = l;
}

// ---------------------------------------------------------------------------
// CSR build
// ---------------------------------------------------------------------------
__global__ void hist_k(const int* __restrict__ ei, int* __restrict__ deg)
{
    int e = blockIdx.x * blockDim.x + threadIdx.x;
    if (e < EE) atomicAdd(&deg[ei[EE + e]], 1);
}

__global__ __launch_bounds__(1024)
void scan_k(const int* __restrict__ deg, int* __restrict__ row_ptr,
            int* __restrict__ pos)
{
    __shared__ int part[1024];
    const int t = threadIdx.x;
    const int chunk = (NN + 1023) / 1024;
    const int i0 = t * chunk;
    const int i1 = min(i0 + chunk, NN);
    int s = 0;
    for (int i = i0; i < i1; ++i) s += deg[i];
    part[t] = s;
    __syncthreads();
    for (int off = 1; off < 1024; off <<= 1) {
        int v = (t >= off) ? part[t - off] : 0;
        __syncthreads();
        part[t] += v;
        __syncthreads();
    }
    int run = (t == 0) ? 0 : part[t - 1];
    for (int i = i0; i < i1; ++i) {
        const int d = deg[i];
        row_ptr[i] = run;
        pos[i] = run;
        run += d;
    }
    if (t == 0) row_ptr[NN] = part[1023];
}

__global__ void fill_k(const int* __restrict__ ei, int* __restrict__ pos,
                       int* __restrict__ eidx)
{
    int e = blockIdx.x * blockDim.x + threadIdx.x;
    if (e < EE) {
        const int slot = atomicAdd(&pos[ei[EE + e]], 1);
        eidx[slot] = ei[e];
    }
}

// ---------------------------------------------------------------------------
// gather v3: coalesced reads AND coalesced packed writes via LDS staging.
// Block 512 thr = 16 nodes x 32 lanes.
// Phase 1: each 32-lane group aggregates one node (512B contiguous row per
//   edge, 4-deep unroll), ReLU, hi/lo split, park in LDS.
// Phase 2 (after barrier): t<256 write hi, t>=256 write lo; thread (nl,o)
//   reads 16B from LDS, stores 16B packed -> 256B contiguous runs.
// ---------------------------------------------------------------------------
__global__ __launch_bounds__(512)
void gather_pk(const float* __restrict__ base, const float* __restrict__ T1,
               const int* __restrict__ row_ptr, const int* __restrict__ eidx,
               ushort* __restrict__ Xh, ushort* __restrict__ Xl)
{
    __shared__ ushort lds_h[16][136];    // pad 8 shorts: destagger banks
    __shared__ ushort lds_l[16][136];
    const int t   = threadIdx.x;
    const int grp = t >> 5;              // node within block (0..15)
    const int ln  = t & 31;              // lane within group
    const int n   = blockIdx.x * 16 + grp;

    const int e0 = row_ptr[n], e1 = row_ptr[n + 1];
    float4 a0 = *(const float4*)&base[(size_t)n * HH + ln * 4];
    float4 a1 = {0,0,0,0}, a2 = {0,0,0,0}, a3 = {0,0,0,0};
    int e = e0;
    for (; e + 4 <= e1; e += 4) {
        const int s0 = eidx[e], s1 = eidx[e+1], s2 = eidx[e+2], s3 = eidx[e+3];
        const float4 v0 = *(const float4*)&T1[(size_t)s0 * HH + ln * 4];
        const float4 v1 = *(const float4*)&T1[(size_t)s1 * HH + ln * 4];
        const float4 v2 = *(const float4*)&T1[(size_t)s2 * HH + ln * 4];
        const float4 v3 = *(const float4*)&T1[(size_t)s3 * HH + ln * 4];
        a0.x += v0.x; a0.y += v0.y; a0.z += v0.z; a0.w += v0.w;
        a1.x += v1.x; a1.y += v1.y; a1.z += v1.z; a1.w += v1.w;
        a2.x += v2.x; a2.y += v2.y; a2.z += v2.z; a2.w += v2.w;
        a3.x += v3.x; a3.y += v3.y; a3.z += v3.z; a3.w += v3.w;
    }
    for (; e < e1; ++e) {
        const int s = eidx[e];
        const float4 v = *(const float4*)&T1[(size_t)s * HH + ln * 4];
        a0.x += v.x; a0.y += v.y; a0.z += v.z; a0.w += v.w;
    }
    float v[4];
    v[0] = fmaxf((a0.x + a1.x) + (a2.x + a3.x), 0.f);
    v[1] = fmaxf((a0.y + a1.y) + (a2.y + a3.y), 0.f);
    v[2] = fmaxf((a0.z + a1.z) + (a2.z + a3.z), 0.f);
    v[3] = fmaxf((a0.w + a1.w) + (a2.w + a3.w), 0.f);
    ushort4 h4, l4;
    {
        ushort hh; float hf;
        hh = bf16rn(v[0]); hf = __uint_as_float((uint)hh << 16); h4.x = hh; l4.x = bf16rn(v[0] - hf);
        hh = bf16rn(v[1]); hf = __uint_as_float((uint)hh << 16); h4.y = hh; l4.y = bf16rn(v[1] - hf);
        hh = bf16rn(v[2]); hf = __uint_as_float((uint)hh << 16); h4.z = hh; l4.z = bf16rn(v[2] - hf);
        hh = bf16rn(v[3]); hf = __uint_as_float((uint)hh << 16); h4.w = hh; l4.w = bf16rn(v[3] - hf);
    }
    *(ushort4*)&lds_h[grp][ln * 4] = h4;
    *(ushort4*)&lds_l[grp][ln * 4] = l4;
    __syncthreads();

    // phase 2: packed stores (hi by t<256, lo by t>=256)
    const int nl = t & 15;
    const int o  = (t >> 4) & 15;
    const size_t addr = ((size_t)blockIdx.x * 4 + (o >> 2)) * 512
                      + (size_t)((o & 3) * 16 + nl) * 8;
    if (t < 256) {
        *(uint4*)&Xh[addr] = *(const uint4*)&lds_h[nl][o * 8];
    } else {
        *(uint4*)&Xl[addr] = *(const uint4*)&lds_l[nl][o * 8];
    }
}

// gather for layer 5: fp32, in-place on base (linear), no relu
__global__ __launch_bounds__(256)
void gather_f32(const float* __restrict__ T1, const int* __restrict__ row_ptr,
                const int* __restrict__ eidx, float* __restrict__ X)
{
    const int n  = blockIdx.x * 8 + (threadIdx.x >> 5);
    const int f4 = threadIdx.x & 31;
    if (n >= NN) return;
    const int e0 = row_ptr[n], e1 = row_ptr[n + 1];
    float4 a0 = *(const float4*)&X[(size_t)n * HH + f4 * 4];
    float4 a1 = {0,0,0,0}, a2 = {0,0,0,0}, a3 = {0,0,0,0};
    int e = e0;
    for (; e + 4 <= e1; e += 4) {
        const int s0 = eidx[e], s1 = eidx[e+1], s2 = eidx[e+2], s3 = eidx[e+3];
        const float4 v0 = *(const float4*)&T1[(size_t)s0 * HH + f4 * 4];
        const float4 v1 = *(const float4*)&T1[(size_t)s1 * HH + f4 * 4];
        const float4 v2 = *(const float4*)&T1[(size_t)s2 * HH + f4 * 4];
        const float4 v3 = *(const float4*)&T1[(size_t)s3 * HH + f4 * 4];
        a0.x += v0.x; a0.y += v0.y; a0.z += v0.z; a0.w += v0.w;
        a1.x += v1.x; a1.y += v1.y; a1.z += v1.z; a1.w += v1.w;
        a2.x += v2.x; a2.y += v2.y; a2.z += v2.z; a2.w += v2.w;
        a3.x += v3.x; a3.y += v3.y; a3.z += v3.z; a3.w += v3.w;
    }
    for (; e < e1; ++e) {
        const int s = eidx[e];
        const float4 v = *(const float4*)&T1[(size_t)s * HH + f4 * 4];
        a0.x += v.x; a0.y += v.y; a0.z += v.z; a0.w += v.w;
    }
    float4 acc;
    acc.x = (a0.x + a1.x) + (a2.x + a3.x);
    acc.y = (a0.y + a1.y) + (a2.y + a3.y);
    acc.z = (a0.z + a1.z) + (a2.z + a3.z);
    acc.w = (a0.w + a1.w) + (a2.w + a3.w);
    *(float4*)&X[(size_t)n * HH + f4 * 4] = acc;
}

__global__ void zero_k(float* __restrict__ p, int n)
{
    int i = blockIdx.x * blockDim.x + threadIdx.x;
    if (i < n) p[i] = 0.f;
}

__global__ __launch_bounds__(256)
void bn_stats(const float* __restrict__ x5, float* __restrict__ stats)
{
    __shared__ float sh_s[256], sh_q[256];
    const int f    = threadIdx.x & 127;
    const int half = threadIdx.x >> 7;
    const int rpb  = (NN + gridDim.x - 1) / gridDim.x;
    const int r0   = blockIdx.x * rpb;
    const int r1   = min(r0 + rpb, NN);
    float s = 0.f, q = 0.f;
    for (int r = r0 + half; r < r1; r += 2) {
        const float v = x5[(size_t)r * HH + f];
        s += v; q += v * v;
    }
    sh_s[threadIdx.x] = s; sh_q[threadIdx.x] = q;
    __syncthreads();
    if (half == 0) {
        s += sh_s[128 + f]; q += sh_q[128 + f];
        atomicAdd(&stats[f], s);
        atomicAdd(&stats[128 + f], q);
    }
}

__global__ __launch_bounds__(128)
void pool_sum(const float* __restrict__ x5, const int* __restrict__ batch,
              float* __restrict__ pool)
{
    const int f  = threadIdx.x;
    const int n0 = blockIdx.x * 64;
    const int n1 = min(n0 + 64, NN);
    float acc = 0.f;
    int curg = batch[n0];
    for (int n = n0; n < n1; ++n) {
        const int g = batch[n];
        if (g != curg) {
            atomicAdd(&pool[(size_t)curg * HH + f], acc);
            acc = 0.f; curg = g;
        }
        acc += x5[(size_t)n * HH + f];
    }
    atomicAdd(&pool[(size_t)curg * HH + f], acc);
}

__global__ __launch_bounds__(128)
void finalize(const float* __restrict__ stats, const float* __restrict__ pool,
              const int* __restrict__ batch,
              const float* __restrict__ gamma, const float* __restrict__ beta,
              const float* __restrict__ lin_w, const float* __restrict__ lin_b,
              float* __restrict__ out)
{
    const int g = blockIdx.x, f = threadIdx.x;
    __shared__ int seg[2];
    if (f < 2) {
        const int target = g + f;
        int lo = 0, hi = NN;
        while (lo < hi) {
            const int mid = (lo + hi) >> 1;
            if (batch[mid] < target) lo = mid + 1; else hi = mid;
        }
        seg[f] = lo;
    }
    __syncthreads();
    const float c   = (float)(seg[1] - seg[0]);
    const float mu  = stats[f] * (1.0f / NN);
    const float var = stats[128 + f] * (1.0f / NN) - mu * mu;
    const float scale = gamma[f] * rsqrtf(var + BN_EPS);
    const float pm = pool[(size_t)g * HH + f] / fmaxf(c, 1.0f);
    __shared__ float sh[128];
    sh[f] = (pm - mu) * scale + beta[f];
    __syncthreads();
    if (f < CC) {
        float s = lin_b[f];
        #pragma unroll 8
        for (int k = 0; k < HH; ++k) s += sh[k] * lin_w[f * HH + k];
        out[(size_t)g * CC + f] = s;
    }
}

extern "C" void kernel_launch(void* const* d_in, const int* in_sizes, int n_in,
                              void* d_out, int out_size, void* d_ws, size_t ws_size,
                              hipStream_t stream)
{
    const float* x       = (const float*)d_in[0];
    const int*   ei      = (const int*)d_in[1];
    const int*   batch   = (const int*)d_in[2];
    const float* w1_rel  = (const float*)d_in[3];
    const float* w1_root = (const float*)d_in[4];
    const float* b1      = (const float*)d_in[5];
    const float* w2_rel  = (const float*)d_in[6];
    const float* w2_root = (const float*)d_in[7];
    const float* b2      = (const float*)d_in[8];
    const float* w3_rel  = (const float*)d_in[9];
    const float* w3_root = (const float*)d_in[10];
    const float* b3      = (const float*)d_in[11];
    const float* w4_rel  = (const float*)d_in[12];
    const float* w4_root = (const float*)d_in[13];
    const float* b4      = (const float*)d_in[14];
    const float* w5_rel  = (const float*)d_in[15];   // [128, 512]
    const float* w5_root = (const float*)d_in[16];   // [128, 512]
    const float* b5      = (const float*)d_in[17];
    const float* gamma   = (const float*)d_in[18];
    const float* beta    = (const float*)d_in[19];
    const float* lin_w   = (const float*)d_in[20];
    const float* lin_b   = (const float*)d_in[21];
    float* out = (float*)d_out;

    const size_t NH = (size_t)NN * HH;   // 2,560,000
    float*  XR  = (float*)d_ws;          // root GEMM out; becomes X5 in-place
    float*  T1  = XR + NH;               // rel GEMM out
    ushort* X1h = (ushort*)(T1 + NH);    // packed per-layer activations
    ushort* X1l = X1h + NH;
    ushort* X2h = X1l + NH;
    ushort* X2l = X2h + NH;
    ushort* X3h = X2l + NH;
    ushort* X3l = X3h + NH;
    ushort* X4h = X3l + NH;
    ushort* X4l = X4h + NH;
    const int K1P = 224;                 // 200 padded to 7*32
    ushort* W1h = X4l + NH;              // packed combined [256][K1P]
    ushort* W1l = W1h + 256 * K1P;
    ushort* W2h = W1l + 256 * K1P;       // packed [256][128] x3
    ushort* W2l = W2h + 256 * 128;
    ushort* W3h = W2l + 256 * 128;
    ushort* W3l = W3h + 256 * 128;
    ushort* W4h = W3l + 256 * 128;
    ushort* W4l = W4h + 256 * 128;
    ushort* W5h = W4l + 256 * 128;       // packed [256][512]
    ushort* W5l = W5h + 256 * 512;
    float*  STATS = (float*)(W5l + 256 * 512);   // 256
    float*  POOL  = STATS + 256;                 // GG*HH
    int* row_ptr = (int*)(POOL + (size_t)GG * HH);  // NN+1
    int* pos     = row_ptr + (NN + 1);
    int* deg     = pos + NN;
    int* eidx    = deg + NN;
    const size_t need = (size_t)(eidx + EE) - (size_t)d_ws;
    if (ws_size < need) return;

    // packed layer-1 input aliases X2h..X3l (dead once L1 GEMM completes)
    ushort* XPh = X2h;                       // 20000*224 ushorts
    ushort* XPl = X2h + (size_t)NN * K1P;

    const dim3 blk(256);
    const int ggw   = NN / RPB;             // 250 blocks x 512 thr
    const int gedge = (EE + 255) / 256;
    const int ggpk  = NN / 16;              // 1250 blocks (gather_pk, pack_x)
    const int ggath = (NN + 7) / 8;         // gather_f32

    zero_k<<<(256 + GG * HH + 255) / 256, blk, 0, stream>>>(STATS, 256 + GG * HH);
    zero_k<<<(NN + 255) / 256, blk, 0, stream>>>((float*)deg, NN);

    // CSR build
    hist_k<<<gedge, blk, 0, stream>>>(ei, deg);
    scan_k<<<1, dim3(1024), 0, stream>>>(deg, row_ptr, pos);
    fill_k<<<gedge, blk, 0, stream>>>(ei, pos, eidx);

    // weight splits (fragment-packed) + layer-1 input pack
    split_w<<<(256 * K1P + 255) / 256, blk, 0, stream>>>(w1_root, w1_rel, FIN, K1P, W1h, W1l, 256 * K1P);
    split_w<<<(256 * 128 + 255) / 256, blk, 0, stream>>>(w2_root, w2_rel, HH, 128, W2h, W2l, 256 * 128);
    split_w<<<(256 * 128 + 255) / 256, blk, 0, stream>>>(w3_root, w3_rel, HH, 128, W3h, W3l, 256 * 128);
    split_w<<<(256 * 128 + 255) / 256, blk, 0, stream>>>(w4_root, w4_rel, HH, 128, W4h, W4l, 256 * 128);
    split_w<<<(256 * 512 + 255) / 256, blk, 0, stream>>>(w5_root, w5_rel, 512, 512, W5h, W5l, 256 * 512);
    pack_x<<<ggpk, dim3(448), 0, stream>>>(x, XPh, XPl);

    // layer 1 (K=224 packed)
    gemm_pk<7><<<ggw, dim3(512), 0, stream>>>(XPh, XPl, W1h, W1l, b1, XR, T1);
    gather_pk<<<ggpk, dim3(512), 0, stream>>>(XR, T1, row_ptr, eidx, X1h, X1l);
    // layers 2-4 (K=128 packed)
    gemm_pk<4><<<ggw, dim3(512), 0, stream>>>(X1h, X1l, W2h, W2l, b2, XR, T1);
    gather_pk<<<ggpk, dim3(512), 0, stream>>>(XR, T1, row_ptr, eidx, X2h, X2l);
    gemm_pk<4><<<ggw, dim3(512), 0, stream>>>(X2h, X2l, W3h, W3l, b3, XR, T1);
    gather_pk<<<ggpk, dim3(512), 0, stream>>>(XR, T1, row_ptr, eidx, X3h, X3l);
    gemm_pk<4><<<ggw, dim3(512), 0, stream>>>(X3h, X3l, W4h, W4l, b4, XR, T1);
    gather_pk<<<ggpk, dim3(512), 0, stream>>>(XR, T1, row_ptr, eidx, X4h, X4l);
    // layer 5: packed concat over X1..X4, K=512, single dispatch
    gemm_pk4<<<ggw, dim3(512), 0, stream>>>(X1h, X1l, X2h, X2l, X3h, X3l, X4h, X4l,
                                            W5h, W5l, b5, XR, T1);
    gather_f32<<<ggath, blk, 0, stream>>>(T1, row_ptr, eidx, XR);   // X5 := XR in-place

    // BN stats, pooling, epilogue
    bn_stats<<<80, blk, 0, stream>>>(XR, STATS);
    pool_sum<<<(NN + 63) / 64, dim3(128), 0, stream>>>(XR, batch, POOL);
    finalize<<<GG, dim3(128), 0, stream>>>(STATS, POOL, batch, gamma, beta, lin_w, lin_b, out);
}